// Round 20
// baseline (158.017 us; speedup 1.0000x reference)
//
#include <hip/hip_runtime.h>
#include <math.h>

// 2-layer GAT (PyG GATConv), N=50000, E=1.6M, IN=256.
// Round 20 = round 19 (155.6us) with ONE change:
//  - sort_place + hist: 4x vectorized (int4 loads of dst/src, 4 independent
//    LDS atomics + 4 scattered stores per thread-iteration). r19 showed
//    place_nt = 42us at VALUBusy 9.8% — latency-bound scatter with MLP=1;
//    this quadruples outstanding stores per thread.
//  - NT (32-node fdot2), AGG (4 nodes/wave), scans, fat-kernel structure:
//    identical to round 19.

#define LEAK 0.2f
#define EPSV 1e-16f
#define CHUNK 2048           // edges per sort block (divisible by 4)
#define BSH 6                // bucket shift: 64 nodes per bucket
#define MAXB 1024            // >= NBUCK (782)
#define LOG2E 1.44269504088896340736f

typedef __attribute__((ext_vector_type(4))) _Float16 half4;
typedef __attribute__((ext_vector_type(2))) _Float16 half2v;
typedef __attribute__((ext_vector_type(2))) __fp16 fp16v2;

#if defined(__has_builtin)
#if __has_builtin(__builtin_amdgcn_fdot2)
#define HAVE_FDOT2 1
#endif
#if __has_builtin(__builtin_amdgcn_exp2f)
#define HAVE_EXP2 1
#endif
#if __has_builtin(__builtin_amdgcn_cvt_pkrtz)
#define HAVE_PKRTZ 1
#endif
#endif

__device__ __forceinline__ float fast_exp2(float x) {
#ifdef HAVE_EXP2
    return __builtin_amdgcn_exp2f(x);
#else
    return exp2f(x);
#endif
}

// elu negative branch via exp2; abs err ~1e-7 (threshold 2.7e-3)
__device__ __forceinline__ float elu_f(float v) {
    return (v > 0.f) ? v : (fast_exp2(v * LOG2E) - 1.f);
}

__device__ __forceinline__ half2v pack2(float a, float b) {
#ifdef HAVE_PKRTZ
    union { fp16v2 f; half2v h; } u;
    u.f = __builtin_amdgcn_cvt_pkrtz(a, b);
    return u.h;
#else
    half2v r; r.x = (_Float16)a; r.y = (_Float16)b; return r;
#endif
}

__device__ __forceinline__ half2v u2h(unsigned v) {
    union { unsigned u; half2v h; } c; c.u = v; return c.h;
}

__device__ __forceinline__ float dot2f(unsigned a, unsigned b, float c) {
    union { unsigned u; half2v h; } ua, ub;
    ua.u = a; ub.u = b;
#ifdef HAVE_FDOT2
    return __builtin_amdgcn_fdot2(ua.h, ub.h, c, false);
#else
    return fmaf((float)ua.h.x, (float)ub.h.x,
                fmaf((float)ua.h.y, (float)ub.h.y, c));
#endif
}

// ---------------- node transform body: 32-node tile, fp16-LDS dot2 GEMM ----
template<int K, int H, int CH>
__device__ __forceinline__
void nt_body(unsigned char* smem, int bid,
             const float* __restrict__ x, const float* __restrict__ W,
             const float* __restrict__ a_s, const float* __restrict__ a_d,
             _Float16* __restrict__ xl_out, float* __restrict__ asrc,
             float* __restrict__ adst, int n)
{
    _Float16 (*xsh)[72]  = reinterpret_cast<_Float16(*)[72]>(smem);       // 32r, 4608B
    unsigned (*wskp)[68] = reinterpret_cast<unsigned(*)[68]>(smem + 4608); // 32r, 8704B
    float (*otile)[68]   = reinterpret_cast<float(*)[68]>(smem);          // epilogue

    int tid = threadIdx.x;
    int tx = tid & 15;
    int ty = tid >> 4;
    int nbase = bid * 32;

    float acc[2][4] = {};
    for (int k0 = 0; k0 < K; k0 += 64) {
        __syncthreads();
        #pragma unroll
        for (int rr = 0; rr < 2; ++rr) {
            int r = ty + 16 * rr;
            int node = nbase + r;
            float4 v = make_float4(0.f, 0.f, 0.f, 0.f);
            if (node < n)
                v = *reinterpret_cast<const float4*>(x + (size_t)node * K + k0 + 4 * tx);
            half4 hv;
            hv.x = (_Float16)v.x; hv.y = (_Float16)v.y;
            hv.z = (_Float16)v.z; hv.w = (_Float16)v.w;
            *reinterpret_cast<half4*>(&xsh[r][4 * tx]) = hv;
        }
        #pragma unroll
        for (int rr = 0; rr < 2; ++rr) {
            int kp = ty + 16 * rr;   // 0..31
            const float* w0 = W + (size_t)(k0 + 2 * kp) * 64 + 4 * tx;
            float4 wa = *reinterpret_cast<const float4*>(w0);
            float4 wb = *reinterpret_cast<const float4*>(w0 + 64);
            union { half2v h; unsigned u; } p0, p1, p2, p3;
            p0.h.x = (_Float16)wa.x; p0.h.y = (_Float16)wb.x;
            p1.h.x = (_Float16)wa.y; p1.h.y = (_Float16)wb.y;
            p2.h.x = (_Float16)wa.z; p2.h.y = (_Float16)wb.z;
            p3.h.x = (_Float16)wa.w; p3.h.y = (_Float16)wb.w;
            uint4 pk; pk.x = p0.u; pk.y = p1.u; pk.z = p2.u; pk.w = p3.u;
            *reinterpret_cast<uint4*>(&wskp[kp][4 * tx]) = pk;
        }
        __syncthreads();
        #pragma unroll 2
        for (int k8 = 0; k8 < 8; ++k8) {
            uint4 wf0 = *reinterpret_cast<const uint4*>(&wskp[k8 * 4 + 0][4 * tx]);
            uint4 wf1 = *reinterpret_cast<const uint4*>(&wskp[k8 * 4 + 1][4 * tx]);
            uint4 wf2 = *reinterpret_cast<const uint4*>(&wskp[k8 * 4 + 2][4 * tx]);
            uint4 wf3 = *reinterpret_cast<const uint4*>(&wskp[k8 * 4 + 3][4 * tx]);
            #pragma unroll
            for (int rr = 0; rr < 2; ++rr) {
                uint4 xr = *reinterpret_cast<const uint4*>(&xsh[ty + 16 * rr][k8 * 8]);
                acc[rr][0] = dot2f(xr.x, wf0.x, acc[rr][0]);
                acc[rr][1] = dot2f(xr.x, wf0.y, acc[rr][1]);
                acc[rr][2] = dot2f(xr.x, wf0.z, acc[rr][2]);
                acc[rr][3] = dot2f(xr.x, wf0.w, acc[rr][3]);
                acc[rr][0] = dot2f(xr.y, wf1.x, acc[rr][0]);
                acc[rr][1] = dot2f(xr.y, wf1.y, acc[rr][1]);
                acc[rr][2] = dot2f(xr.y, wf1.z, acc[rr][2]);
                acc[rr][3] = dot2f(xr.y, wf1.w, acc[rr][3]);
                acc[rr][0] = dot2f(xr.z, wf2.x, acc[rr][0]);
                acc[rr][1] = dot2f(xr.z, wf2.y, acc[rr][1]);
                acc[rr][2] = dot2f(xr.z, wf2.z, acc[rr][2]);
                acc[rr][3] = dot2f(xr.z, wf2.w, acc[rr][3]);
                acc[rr][0] = dot2f(xr.w, wf3.x, acc[rr][0]);
                acc[rr][1] = dot2f(xr.w, wf3.y, acc[rr][1]);
                acc[rr][2] = dot2f(xr.w, wf3.z, acc[rr][2]);
                acc[rr][3] = dot2f(xr.w, wf3.w, acc[rr][3]);
            }
        }
    }
    __syncthreads();   // reuse smem as f32 out tile
    #pragma unroll
    for (int rr = 0; rr < 2; ++rr) {
        int r = ty + 16 * rr;
        int node = nbase + r;
        otile[r][4 * tx + 0] = acc[rr][0];
        otile[r][4 * tx + 1] = acc[rr][1];
        otile[r][4 * tx + 2] = acc[rr][2];
        otile[r][4 * tx + 3] = acc[rr][3];
        if (node < n) {
            half4 hv;
            hv.x = (_Float16)acc[rr][0]; hv.y = (_Float16)acc[rr][1];
            hv.z = (_Float16)acc[rr][2]; hv.w = (_Float16)acc[rr][3];
            *reinterpret_cast<half4*>(xl_out + (size_t)node * 64 + 4 * tx) = hv;
        }
    }
    __syncthreads();
    for (int t = tid; t < 32 * H; t += 256) {
        int nl = t / H, h = t - nl * H;
        int node = nbase + nl;
        if (node < n) {
            float s = 0.f, d = 0.f;
            #pragma unroll
            for (int c = 0; c < CH; ++c) {
                float v = otile[nl][h * CH + c];
                s = fmaf(v, a_s[h * CH + c], s);
                d = fmaf(v, a_d[h * CH + c], d);
            }
            asrc[node * H + h] = s * LOG2E;
            adst[node * H + h] = d * LOG2E;
        }
    }
}

// standalone NT kernel (layer 2)
template<int K, int H, int CH>
__global__ __launch_bounds__(256)
void node_transform(const float* __restrict__ x, const float* __restrict__ W,
                    const float* __restrict__ a_s, const float* __restrict__ a_d,
                    _Float16* __restrict__ xl_out, float* __restrict__ asrc,
                    float* __restrict__ adst, int n)
{
    __shared__ __align__(16) unsigned char smem[13312];
    nt_body<K, H, CH>(smem, blockIdx.x, x, W, a_s, a_d, xl_out, asrc, adst, n);
}

// fat 1: blocks [0,NSB) = dst histogram (4x vectorized); rest = NT1 tiles
template<int K, int H, int CH>
__global__ __launch_bounds__(256)
void hist_nt(const float* __restrict__ x, const float* __restrict__ W,
             const float* __restrict__ a_s, const float* __restrict__ a_d,
             _Float16* __restrict__ xl_out, float* __restrict__ asrc,
             float* __restrict__ adst, int n,
             const int* __restrict__ dst, int E,
             int* __restrict__ hist_mat, int NBUCK, int NSB, int ntStart)
{
    __shared__ __align__(16) unsigned char smem[13312];
    if ((int)blockIdx.x < NSB) {
        int* h = reinterpret_cast<int*>(smem);
        int tid = threadIdx.x, chunk = blockIdx.x;
        for (int b = tid; b < NBUCK; b += 256) h[b] = 0;
        __syncthreads();
        int base = chunk * CHUNK, end = min(base + CHUNK, E);
        for (int i = base + tid * 4; i < end; i += 1024) {
            int4 d4 = *reinterpret_cast<const int4*>(dst + i);
            atomicAdd(&h[d4.x >> BSH], 1);
            atomicAdd(&h[d4.y >> BSH], 1);
            atomicAdd(&h[d4.z >> BSH], 1);
            atomicAdd(&h[d4.w >> BSH], 1);
        }
        __syncthreads();
        for (int b = tid; b < NBUCK; b += 256)
            hist_mat[b * NSB + chunk] = h[b];
    } else {
        nt_body<K, H, CH>(smem, ntStart + (int)blockIdx.x - NSB,
                          x, W, a_s, a_d, xl_out, asrc, adst, n);
    }
}

// fat 2: blocks [0,NSB) = sort_place (4x vectorized); rest = NT1 tiles
template<int K, int H, int CH>
__global__ __launch_bounds__(256)
void place_nt(const float* __restrict__ x, const float* __restrict__ W,
              const float* __restrict__ a_s, const float* __restrict__ a_d,
              _Float16* __restrict__ xl_out, float* __restrict__ asrc,
              float* __restrict__ adst, int n,
              const int* __restrict__ src, const int* __restrict__ dst, int E,
              const int* __restrict__ scanned, int NBUCK, int NSB,
              unsigned* __restrict__ ssrc, int ntStart)
{
    __shared__ __align__(16) unsigned char smem[13312];
    if ((int)blockIdx.x < NSB) {
        int* cur = reinterpret_cast<int*>(smem);
        int tid = threadIdx.x, chunk = blockIdx.x;
        for (int b = tid; b < NBUCK; b += 256) cur[b] = scanned[b * NSB + chunk];
        __syncthreads();
        int base = chunk * CHUNK, end = min(base + CHUNK, E);
        for (int i = base + tid * 4; i < end; i += 1024) {
            int4 d4 = *reinterpret_cast<const int4*>(dst + i);
            int4 s4 = *reinterpret_cast<const int4*>(src + i);
            int r0 = atomicAdd(&cur[d4.x >> BSH], 1);
            int r1 = atomicAdd(&cur[d4.y >> BSH], 1);
            int r2 = atomicAdd(&cur[d4.z >> BSH], 1);
            int r3 = atomicAdd(&cur[d4.w >> BSH], 1);
            ssrc[r0] = ((unsigned)s4.x << BSH) | (unsigned)(d4.x & 63);
            ssrc[r1] = ((unsigned)s4.y << BSH) | (unsigned)(d4.y & 63);
            ssrc[r2] = ((unsigned)s4.z << BSH) | (unsigned)(d4.z & 63);
            ssrc[r3] = ((unsigned)s4.w << BSH) | (unsigned)(d4.w & 63);
        }
    } else {
        nt_body<K, H, CH>(smem, ntStart + (int)blockIdx.x - NSB,
                          x, W, a_s, a_d, xl_out, asrc, adst, n);
    }
}

// fat 3: blocks [0,NBUCK) = bucket_nodesort; rest = NT1 tiles
template<int K, int H, int CH>
__global__ __launch_bounds__(256)
void nodesort_nt(const float* __restrict__ x, const float* __restrict__ W,
                 const float* __restrict__ a_s, const float* __restrict__ a_d,
                 _Float16* __restrict__ xl_out, float* __restrict__ asrc,
                 float* __restrict__ adst, int n,
                 const unsigned* __restrict__ ssrc, const int* __restrict__ bstart,
                 unsigned short* __restrict__ ssrc2, int* __restrict__ offs,
                 int NBUCK, int E, int ntStart)
{
    __shared__ __align__(16) unsigned char smem[13312];
    if ((int)blockIdx.x < NBUCK) {
        int* cnt  = reinterpret_cast<int*>(smem);          // 64
        int* base_ = cnt + 64;                             // 64
        int bk = blockIdx.x, tid = threadIdx.x;
        int beg = bstart[bk], end = bstart[bk + 1];
        if (tid < 64) cnt[tid] = 0;
        __syncthreads();
        for (int i = beg + tid; i < end; i += 256)
            atomicAdd(&cnt[ssrc[i] & 63], 1);
        __syncthreads();
        if (tid == 0) {
            int r = 0;
            for (int j = 0; j < 64; ++j) { int c = cnt[j]; base_[j] = r; r += c; }
        }
        __syncthreads();
        if (tid < 64) {
            int node = (bk << BSH) + tid;
            if (node < n) offs[node] = beg + base_[tid];
            cnt[tid] = 0;    // reuse as cursor
        }
        __syncthreads();
        for (int i = beg + tid; i < end; i += 256) {
            unsigned e = ssrc[i];
            int dl = e & 63;
            int r = atomicAdd(&cnt[dl], 1);
            ssrc2[beg + base_[dl] + r] = (unsigned short)(e >> BSH);
        }
        if (bk == 0 && tid == 0) offs[n] = E;
    } else {
        nt_body<K, H, CH>(smem, ntStart + (int)blockIdx.x - NBUCK,
                          x, W, a_s, a_d, xl_out, asrc, adst, n);
    }
}

#define SCAN_SZ 2048
__global__ __launch_bounds__(256)
void scan1_kernel(const int* __restrict__ in, int* __restrict__ part,
                  int* __restrict__ sums, int m)
{
    __shared__ int lds[256];
    int base = blockIdx.x * SCAN_SZ;
    int t = threadIdx.x;
    int v[8]; int s = 0;
    #pragma unroll
    for (int j = 0; j < 8; ++j) {
        int idx = base + t * 8 + j;
        v[j] = (idx < m) ? in[idx] : 0;
        s += v[j];
    }
    lds[t] = s;
    __syncthreads();
    for (int off = 1; off < 256; off <<= 1) {
        int a = (t >= off) ? lds[t - off] : 0;
        __syncthreads();
        lds[t] += a;
        __syncthreads();
    }
    int run = lds[t] - s;
    if (t == 255) sums[blockIdx.x] = lds[t];
    #pragma unroll
    for (int j = 0; j < 8; ++j) {
        int idx = base + t * 8 + j;
        if (idx < m) part[idx] = run;
        run += v[j];
    }
}

__global__ __launch_bounds__(256)
void scan3_kernel(const int* __restrict__ part, const int* __restrict__ sums,
                  int* __restrict__ outp, int* __restrict__ bstart,
                  int m, int NSB, int NBUCK, int E, int nb)
{
    __shared__ int spre[512];
    int i = blockIdx.x * 256 + threadIdx.x;
    if (threadIdx.x == 0) {
        int r = 0;
        for (int j = 0; j < nb; ++j) { spre[j] = r; r += sums[j]; }
    }
    __syncthreads();
    if (i < m) {
        int v = part[i] + spre[i / SCAN_SZ];
        outp[i] = v;
        if (i % NSB == 0) bstart[i / NSB] = v;
    }
    if (i == 0) bstart[NBUCK] = E;
}

// ---------------- aggregation: 4 nodes/wave, 2 groups x 8 lanes per node ----
template<int H, int CH, int MODE>
__global__ __launch_bounds__(256)
void aggregate_csr(const int* __restrict__ offs, const unsigned short* __restrict__ ssrc2,
                   const float* __restrict__ asrc, const float* __restrict__ adst,
                   const _Float16* __restrict__ xl, const float* __restrict__ bias,
                   float* __restrict__ outp, int n)
{
    int d = blockIdx.x * 16 + (threadIdx.x >> 4);
    if (d >= n) return;
    int sub = threadIdx.x & 15;
    int g = sub >> 3;           // 0..1 edge group (per quarter-wave)
    int s8 = sub & 7;           // channel octet
    int h = (s8 * 8) / CH;      // L1 (CH=8): h=s8; L2 (CH=16): h=s8>>1

    float ad = adst[(unsigned)d * H + h];
    int beg = offs[d], end = offs[d + 1];

    half2v a01 = {(_Float16)0.f, (_Float16)0.f};
    half2v a23 = a01, a45 = a01, a67 = a01;
    float den = 0.f;

    #pragma unroll 4
    for (int i = beg + g; i < end; i += 2) {
        int s = (int)ssrc2[i];
        float l = asrc[(unsigned)s * H + h] + ad;
        l = fmaxf(l, LEAK * l);            // leaky-relu (logits prescaled)
        float p = fast_exp2(l);
        uint4 hv = *reinterpret_cast<const uint4*>(xl + ((unsigned)s << 6) + 8u * s8);
        den += p;
        half2v ph = pack2(p, p);
        a01 = u2h(hv.x) * ph + a01;        // v_pk_fma_f16
        a23 = u2h(hv.y) * ph + a23;
        a45 = u2h(hv.z) * ph + a45;
        a67 = u2h(hv.w) * ph + a67;
    }

    // convert f16 chains to f32; combine 2 groups (xor 8, within quarter-wave)
    float v8[8];
    v8[0] = (float)a01.x; v8[1] = (float)a01.y;
    v8[2] = (float)a23.x; v8[3] = (float)a23.y;
    v8[4] = (float)a45.x; v8[5] = (float)a45.y;
    v8[6] = (float)a67.x; v8[7] = (float)a67.y;
    #pragma unroll
    for (int j = 0; j < 8; ++j) v8[j] += __shfl_xor(v8[j], 8);
    den += __shfl_xor(den, 8);

    // self-loop (f32, once per node)
    {
        float l = asrc[(unsigned)d * H + h] + ad;
        l = fmaxf(l, LEAK * l);
        float ps = fast_exp2(l);
        uint4 hv = *reinterpret_cast<const uint4*>(xl + ((unsigned)d << 6) + 8u * s8);
        den += ps;
        half2v x01 = u2h(hv.x), x23 = u2h(hv.y), x45 = u2h(hv.z), x67 = u2h(hv.w);
        v8[0] = fmaf(ps, (float)x01.x, v8[0]);
        v8[1] = fmaf(ps, (float)x01.y, v8[1]);
        v8[2] = fmaf(ps, (float)x23.x, v8[2]);
        v8[3] = fmaf(ps, (float)x23.y, v8[3]);
        v8[4] = fmaf(ps, (float)x45.x, v8[4]);
        v8[5] = fmaf(ps, (float)x45.y, v8[5]);
        v8[6] = fmaf(ps, (float)x67.x, v8[6]);
        v8[7] = fmaf(ps, (float)x67.y, v8[7]);
    }
    float inv = 1.f / fmaxf(den, EPSV);
    #pragma unroll
    for (int j = 0; j < 8; ++j) v8[j] *= inv;

    if (MODE == 1) {
        if (g == 0) {   // lanes sub 0..7 of each quarter-wave write their node
            float4 ba = reinterpret_cast<const float4*>(bias)[2 * s8];
            float4 bb = reinterpret_cast<const float4*>(bias)[2 * s8 + 1];
            float o0 = elu_f(v8[0] + ba.x), o1 = elu_f(v8[1] + ba.y);
            float o2 = elu_f(v8[2] + ba.z), o3 = elu_f(v8[3] + ba.w);
            float o4 = elu_f(v8[4] + bb.x), o5 = elu_f(v8[5] + bb.y);
            float o6 = elu_f(v8[6] + bb.z), o7 = elu_f(v8[7] + bb.w);
            float* op = outp + (size_t)d * 64 + 8 * s8;
            *reinterpret_cast<float4*>(op)     = make_float4(o0, o1, o2, o3);
            *reinterpret_cast<float4*>(op + 4) = make_float4(o4, o5, o6, o7);
        }
    } else {
        // head-mean over H=4 (CH=16): xor 2,4 on s8 bits (within quarter-wave)
        #pragma unroll
        for (int j = 0; j < 8; ++j) {
            v8[j] += __shfl_xor(v8[j], 2);
            v8[j] += __shfl_xor(v8[j], 4);
        }
        if (sub < 2) {   // g==0, s8 in {0,1}: out channels 8*s8..8*s8+7
            float4 ba = reinterpret_cast<const float4*>(bias)[2 * s8];
            float4 bb = reinterpret_cast<const float4*>(bias)[2 * s8 + 1];
            float* op = outp + (size_t)d * 16 + 8 * s8;
            *reinterpret_cast<float4*>(op) = make_float4(
                0.25f * v8[0] + ba.x, 0.25f * v8[1] + ba.y,
                0.25f * v8[2] + ba.z, 0.25f * v8[3] + ba.w);
            *reinterpret_cast<float4*>(op + 4) = make_float4(
                0.25f * v8[4] + bb.x, 0.25f * v8[5] + bb.y,
                0.25f * v8[6] + bb.z, 0.25f * v8[7] + bb.w);
        }
    }
}

// ---------------- host ----------------
extern "C" void kernel_launch(void* const* d_in, const int* in_sizes, int n_in,
                              void* d_out, int out_size, void* d_ws, size_t ws_size,
                              hipStream_t stream)
{
    const float* x      = (const float*)d_in[0];
    const int*   ei     = (const int*)d_in[1];
    const float* W1     = (const float*)d_in[2];
    const float* a_src1 = (const float*)d_in[3];
    const float* a_dst1 = (const float*)d_in[4];
    const float* b1     = (const float*)d_in[5];
    const float* W2     = (const float*)d_in[6];
    const float* a_src2 = (const float*)d_in[7];
    const float* a_dst2 = (const float*)d_in[8];
    const float* b2     = (const float*)d_in[9];
    float* out = (float*)d_out;

    const int n = in_sizes[0] / 256;     // 50000
    const int E = in_sizes[1] / 2;       // 1600000
    const int* src = ei;
    const int* dst = ei + E;

    const int NSB   = (E + CHUNK - 1) / CHUNK;        // 782
    const int NBUCK = (n + 63) >> BSH;                // 782
    const int m     = NBUCK * NSB;                    // 611524
    const int nb    = (m + SCAN_SZ - 1) / SCAN_SZ;    // 299
    const int NTB   = (n + 31) / 32;                  // 1563 (32-node tiles)
    const int T1    = NTB / 3;                        // 521
    const int T2    = NTB / 3;                        // 521
    const int T3    = NTB - T1 - T2;                  // 521

    size_t N64 = (size_t)n * 64;
    size_t N8  = (size_t)n * 8;
    _Float16* xlh  = (_Float16*)d_ws;                 // N*64 fp16 (both layers)
    float* hbuf    = (float*)(xlh + N64);             // N*64 f32 (h)
    float* asrc    = hbuf + N64;                      // N*8
    float* adst    = asrc + N8;                       // N*8
    int*   histm   = (int*)(adst + N8);               // m
    int*   part    = histm + m;                       // m
    int*   scand   = part + m;                        // m
    int*   sums    = scand + m;                       // 512
    int*   bstart  = sums + 512;                      // NBUCK+1 (783)
    int*   offs    = bstart + NBUCK + 1;              // n+1 (50001)
    unsigned* ssrc = (unsigned*)(offs + n + 1);       // E (4B)
    unsigned short* ssrc2 = (unsigned short*)(ssrc + E);   // E (2B)
    (void)ws_size; (void)n_in; (void)out_size;

    // ----- phase A: hist + NT1 tiles [0, T1) -----
    hist_nt<256, 8, 8><<<NSB + T1, 256, 0, stream>>>(
        x, W1, a_src1, a_dst1, xlh, asrc, adst, n, dst, E, histm, NBUCK, NSB, 0);

    // ----- scans -----
    scan1_kernel<<<nb, 256, 0, stream>>>(histm, part, sums, m);
    scan3_kernel<<<(m + 255) / 256, 256, 0, stream>>>(part, sums, scand, bstart,
                                                      m, NSB, NBUCK, E, nb);

    // ----- phase B: sort_place + NT1 tiles [T1, T1+T2) -----
    place_nt<256, 8, 8><<<NSB + T2, 256, 0, stream>>>(
        x, W1, a_src1, a_dst1, xlh, asrc, adst, n,
        src, dst, E, scand, NBUCK, NSB, ssrc, T1);

    // ----- phase C: bucket_nodesort + NT1 tiles [T1+T2, NTB) -----
    nodesort_nt<256, 8, 8><<<NBUCK + T3, 256, 0, stream>>>(
        x, W1, a_src1, a_dst1, xlh, asrc, adst, n,
        ssrc, bstart, ssrc2, offs, NBUCK, E, T1 + T2);

    // ----- Layer 1 aggregate: 256 -> 8x8, concat, +b1, ELU -----
    aggregate_csr<8, 8, 1><<<(n + 15) / 16, 256, 0, stream>>>(offs, ssrc2, asrc, adst,
                                                              xlh, b1, hbuf, n);

    // ----- Layer 2: 64 -> 4x16, mean heads, +b2 -----
    node_transform<64, 4, 16><<<NTB, 256, 0, stream>>>(
        hbuf, W2, a_src2, a_dst2, xlh, asrc, adst, n);
    aggregate_csr<4, 16, 2><<<(n + 15) / 16, 256, 0, stream>>>(offs, ssrc2, asrc, adst,
                                                               xlh, b2, out, n);
}

// Round 21
// 156.093 us; speedup vs baseline: 1.0123x; 1.0123x over previous
//
#include <hip/hip_runtime.h>
#include <math.h>

// 2-layer GAT (PyG GATConv), N=50000, E=1.6M, IN=256.
// Round 21 = round 19 (155.6us; r20's int4 scatter reverted — neutral) with
// ONE change:
//  - scanned-offset matrix TRANSPOSED ([chunk][bucket] via scan3's write):
//    place_nt's cursor init was 782 stride-3128B reads/block (~50KB of
//    scattered, barrier-blocking lines; ~39MB total). Now coalesced
//    (~13 lines/block). scan3's writes become scattered but pipelined.
//  - NT (32-node fdot2), AGG (4 nodes/wave), fat-kernel structure: r19.

#define LEAK 0.2f
#define EPSV 1e-16f
#define CHUNK 2048           // edges per sort block
#define BSH 6                // bucket shift: 64 nodes per bucket
#define MAXB 1024            // >= NBUCK (782)
#define LOG2E 1.44269504088896340736f

typedef __attribute__((ext_vector_type(4))) _Float16 half4;
typedef __attribute__((ext_vector_type(2))) _Float16 half2v;
typedef __attribute__((ext_vector_type(2))) __fp16 fp16v2;

#if defined(__has_builtin)
#if __has_builtin(__builtin_amdgcn_fdot2)
#define HAVE_FDOT2 1
#endif
#if __has_builtin(__builtin_amdgcn_exp2f)
#define HAVE_EXP2 1
#endif
#if __has_builtin(__builtin_amdgcn_cvt_pkrtz)
#define HAVE_PKRTZ 1
#endif
#endif

__device__ __forceinline__ float fast_exp2(float x) {
#ifdef HAVE_EXP2
    return __builtin_amdgcn_exp2f(x);
#else
    return exp2f(x);
#endif
}

// elu negative branch via exp2; abs err ~1e-7 (threshold 2.7e-3)
__device__ __forceinline__ float elu_f(float v) {
    return (v > 0.f) ? v : (fast_exp2(v * LOG2E) - 1.f);
}

__device__ __forceinline__ half2v pack2(float a, float b) {
#ifdef HAVE_PKRTZ
    union { fp16v2 f; half2v h; } u;
    u.f = __builtin_amdgcn_cvt_pkrtz(a, b);
    return u.h;
#else
    half2v r; r.x = (_Float16)a; r.y = (_Float16)b; return r;
#endif
}

__device__ __forceinline__ half2v u2h(unsigned v) {
    union { unsigned u; half2v h; } c; c.u = v; return c.h;
}

__device__ __forceinline__ float dot2f(unsigned a, unsigned b, float c) {
    union { unsigned u; half2v h; } ua, ub;
    ua.u = a; ub.u = b;
#ifdef HAVE_FDOT2
    return __builtin_amdgcn_fdot2(ua.h, ub.h, c, false);
#else
    return fmaf((float)ua.h.x, (float)ub.h.x,
                fmaf((float)ua.h.y, (float)ub.h.y, c));
#endif
}

// ---------------- node transform body: 32-node tile, fp16-LDS dot2 GEMM ----
template<int K, int H, int CH>
__device__ __forceinline__
void nt_body(unsigned char* smem, int bid,
             const float* __restrict__ x, const float* __restrict__ W,
             const float* __restrict__ a_s, const float* __restrict__ a_d,
             _Float16* __restrict__ xl_out, float* __restrict__ asrc,
             float* __restrict__ adst, int n)
{
    _Float16 (*xsh)[72]  = reinterpret_cast<_Float16(*)[72]>(smem);       // 32r, 4608B
    unsigned (*wskp)[68] = reinterpret_cast<unsigned(*)[68]>(smem + 4608); // 32r, 8704B
    float (*otile)[68]   = reinterpret_cast<float(*)[68]>(smem);          // epilogue

    int tid = threadIdx.x;
    int tx = tid & 15;
    int ty = tid >> 4;
    int nbase = bid * 32;

    float acc[2][4] = {};
    for (int k0 = 0; k0 < K; k0 += 64) {
        __syncthreads();
        #pragma unroll
        for (int rr = 0; rr < 2; ++rr) {
            int r = ty + 16 * rr;
            int node = nbase + r;
            float4 v = make_float4(0.f, 0.f, 0.f, 0.f);
            if (node < n)
                v = *reinterpret_cast<const float4*>(x + (size_t)node * K + k0 + 4 * tx);
            half4 hv;
            hv.x = (_Float16)v.x; hv.y = (_Float16)v.y;
            hv.z = (_Float16)v.z; hv.w = (_Float16)v.w;
            *reinterpret_cast<half4*>(&xsh[r][4 * tx]) = hv;
        }
        #pragma unroll
        for (int rr = 0; rr < 2; ++rr) {
            int kp = ty + 16 * rr;   // 0..31
            const float* w0 = W + (size_t)(k0 + 2 * kp) * 64 + 4 * tx;
            float4 wa = *reinterpret_cast<const float4*>(w0);
            float4 wb = *reinterpret_cast<const float4*>(w0 + 64);
            union { half2v h; unsigned u; } p0, p1, p2, p3;
            p0.h.x = (_Float16)wa.x; p0.h.y = (_Float16)wb.x;
            p1.h.x = (_Float16)wa.y; p1.h.y = (_Float16)wb.y;
            p2.h.x = (_Float16)wa.z; p2.h.y = (_Float16)wb.z;
            p3.h.x = (_Float16)wa.w; p3.h.y = (_Float16)wb.w;
            uint4 pk; pk.x = p0.u; pk.y = p1.u; pk.z = p2.u; pk.w = p3.u;
            *reinterpret_cast<uint4*>(&wskp[kp][4 * tx]) = pk;
        }
        __syncthreads();
        #pragma unroll 2
        for (int k8 = 0; k8 < 8; ++k8) {
            uint4 wf0 = *reinterpret_cast<const uint4*>(&wskp[k8 * 4 + 0][4 * tx]);
            uint4 wf1 = *reinterpret_cast<const uint4*>(&wskp[k8 * 4 + 1][4 * tx]);
            uint4 wf2 = *reinterpret_cast<const uint4*>(&wskp[k8 * 4 + 2][4 * tx]);
            uint4 wf3 = *reinterpret_cast<const uint4*>(&wskp[k8 * 4 + 3][4 * tx]);
            #pragma unroll
            for (int rr = 0; rr < 2; ++rr) {
                uint4 xr = *reinterpret_cast<const uint4*>(&xsh[ty + 16 * rr][k8 * 8]);
                acc[rr][0] = dot2f(xr.x, wf0.x, acc[rr][0]);
                acc[rr][1] = dot2f(xr.x, wf0.y, acc[rr][1]);
                acc[rr][2] = dot2f(xr.x, wf0.z, acc[rr][2]);
                acc[rr][3] = dot2f(xr.x, wf0.w, acc[rr][3]);
                acc[rr][0] = dot2f(xr.y, wf1.x, acc[rr][0]);
                acc[rr][1] = dot2f(xr.y, wf1.y, acc[rr][1]);
                acc[rr][2] = dot2f(xr.y, wf1.z, acc[rr][2]);
                acc[rr][3] = dot2f(xr.y, wf1.w, acc[rr][3]);
                acc[rr][0] = dot2f(xr.z, wf2.x, acc[rr][0]);
                acc[rr][1] = dot2f(xr.z, wf2.y, acc[rr][1]);
                acc[rr][2] = dot2f(xr.z, wf2.z, acc[rr][2]);
                acc[rr][3] = dot2f(xr.z, wf2.w, acc[rr][3]);
                acc[rr][0] = dot2f(xr.w, wf3.x, acc[rr][0]);
                acc[rr][1] = dot2f(xr.w, wf3.y, acc[rr][1]);
                acc[rr][2] = dot2f(xr.w, wf3.z, acc[rr][2]);
                acc[rr][3] = dot2f(xr.w, wf3.w, acc[rr][3]);
            }
        }
    }
    __syncthreads();   // reuse smem as f32 out tile
    #pragma unroll
    for (int rr = 0; rr < 2; ++rr) {
        int r = ty + 16 * rr;
        int node = nbase + r;
        otile[r][4 * tx + 0] = acc[rr][0];
        otile[r][4 * tx + 1] = acc[rr][1];
        otile[r][4 * tx + 2] = acc[rr][2];
        otile[r][4 * tx + 3] = acc[rr][3];
        if (node < n) {
            half4 hv;
            hv.x = (_Float16)acc[rr][0]; hv.y = (_Float16)acc[rr][1];
            hv.z = (_Float16)acc[rr][2]; hv.w = (_Float16)acc[rr][3];
            *reinterpret_cast<half4*>(xl_out + (size_t)node * 64 + 4 * tx) = hv;
        }
    }
    __syncthreads();
    for (int t = tid; t < 32 * H; t += 256) {
        int nl = t / H, h = t - nl * H;
        int node = nbase + nl;
        if (node < n) {
            float s = 0.f, d = 0.f;
            #pragma unroll
            for (int c = 0; c < CH; ++c) {
                float v = otile[nl][h * CH + c];
                s = fmaf(v, a_s[h * CH + c], s);
                d = fmaf(v, a_d[h * CH + c], d);
            }
            asrc[node * H + h] = s * LOG2E;
            adst[node * H + h] = d * LOG2E;
        }
    }
}

// standalone NT kernel (layer 2)
template<int K, int H, int CH>
__global__ __launch_bounds__(256)
void node_transform(const float* __restrict__ x, const float* __restrict__ W,
                    const float* __restrict__ a_s, const float* __restrict__ a_d,
                    _Float16* __restrict__ xl_out, float* __restrict__ asrc,
                    float* __restrict__ adst, int n)
{
    __shared__ __align__(16) unsigned char smem[13312];
    nt_body<K, H, CH>(smem, blockIdx.x, x, W, a_s, a_d, xl_out, asrc, adst, n);
}

// fat 1: blocks [0,NSB) = dst histogram; rest = NT1 tiles
template<int K, int H, int CH>
__global__ __launch_bounds__(256)
void hist_nt(const float* __restrict__ x, const float* __restrict__ W,
             const float* __restrict__ a_s, const float* __restrict__ a_d,
             _Float16* __restrict__ xl_out, float* __restrict__ asrc,
             float* __restrict__ adst, int n,
             const int* __restrict__ dst, int E,
             int* __restrict__ hist_mat, int NBUCK, int NSB, int ntStart)
{
    __shared__ __align__(16) unsigned char smem[13312];
    if ((int)blockIdx.x < NSB) {
        int* h = reinterpret_cast<int*>(smem);
        int tid = threadIdx.x, chunk = blockIdx.x;
        for (int b = tid; b < NBUCK; b += 256) h[b] = 0;
        __syncthreads();
        int base = chunk * CHUNK, end = min(base + CHUNK, E);
        for (int i = base + tid; i < end; i += 256)
            atomicAdd(&h[dst[i] >> BSH], 1);
        __syncthreads();
        for (int b = tid; b < NBUCK; b += 256)
            hist_mat[b * NSB + chunk] = h[b];
    } else {
        nt_body<K, H, CH>(smem, ntStart + (int)blockIdx.x - NSB,
                          x, W, a_s, a_d, xl_out, asrc, adst, n);
    }
}

// fat 2: blocks [0,NSB) = sort_place (cursor init from TRANSPOSED scand);
// rest = NT1 tiles
template<int K, int H, int CH>
__global__ __launch_bounds__(256)
void place_nt(const float* __restrict__ x, const float* __restrict__ W,
              const float* __restrict__ a_s, const float* __restrict__ a_d,
              _Float16* __restrict__ xl_out, float* __restrict__ asrc,
              float* __restrict__ adst, int n,
              const int* __restrict__ src, const int* __restrict__ dst, int E,
              const int* __restrict__ scandT, int NBUCK, int NSB,
              unsigned* __restrict__ ssrc, int ntStart)
{
    __shared__ __align__(16) unsigned char smem[13312];
    if ((int)blockIdx.x < NSB) {
        int* cur = reinterpret_cast<int*>(smem);
        int tid = threadIdx.x, chunk = blockIdx.x;
        for (int b = tid; b < NBUCK; b += 256)
            cur[b] = scandT[(size_t)chunk * NBUCK + b];    // coalesced
        __syncthreads();
        int base = chunk * CHUNK, end = min(base + CHUNK, E);
        for (int i = base + tid; i < end; i += 256) {
            int d = dst[i];
            int b = d >> BSH;
            int slot = atomicAdd(&cur[b], 1);
            ssrc[slot] = ((unsigned)src[i] << BSH) | (unsigned)(d & 63);
        }
    } else {
        nt_body<K, H, CH>(smem, ntStart + (int)blockIdx.x - NSB,
                          x, W, a_s, a_d, xl_out, asrc, adst, n);
    }
}

// fat 3: blocks [0,NBUCK) = bucket_nodesort; rest = NT1 tiles
template<int K, int H, int CH>
__global__ __launch_bounds__(256)
void nodesort_nt(const float* __restrict__ x, const float* __restrict__ W,
                 const float* __restrict__ a_s, const float* __restrict__ a_d,
                 _Float16* __restrict__ xl_out, float* __restrict__ asrc,
                 float* __restrict__ adst, int n,
                 const unsigned* __restrict__ ssrc, const int* __restrict__ bstart,
                 unsigned short* __restrict__ ssrc2, int* __restrict__ offs,
                 int NBUCK, int E, int ntStart)
{
    __shared__ __align__(16) unsigned char smem[13312];
    if ((int)blockIdx.x < NBUCK) {
        int* cnt  = reinterpret_cast<int*>(smem);          // 64
        int* base_ = cnt + 64;                             // 64
        int bk = blockIdx.x, tid = threadIdx.x;
        int beg = bstart[bk], end = bstart[bk + 1];
        if (tid < 64) cnt[tid] = 0;
        __syncthreads();
        for (int i = beg + tid; i < end; i += 256)
            atomicAdd(&cnt[ssrc[i] & 63], 1);
        __syncthreads();
        if (tid == 0) {
            int r = 0;
            for (int j = 0; j < 64; ++j) { int c = cnt[j]; base_[j] = r; r += c; }
        }
        __syncthreads();
        if (tid < 64) {
            int node = (bk << BSH) + tid;
            if (node < n) offs[node] = beg + base_[tid];
            cnt[tid] = 0;    // reuse as cursor
        }
        __syncthreads();
        for (int i = beg + tid; i < end; i += 256) {
            unsigned e = ssrc[i];
            int dl = e & 63;
            int r = atomicAdd(&cnt[dl], 1);
            ssrc2[beg + base_[dl] + r] = (unsigned short)(e >> BSH);
        }
        if (bk == 0 && tid == 0) offs[n] = E;
    } else {
        nt_body<K, H, CH>(smem, ntStart + (int)blockIdx.x - NBUCK,
                          x, W, a_s, a_d, xl_out, asrc, adst, n);
    }
}

#define SCAN_SZ 2048
__global__ __launch_bounds__(256)
void scan1_kernel(const int* __restrict__ in, int* __restrict__ part,
                  int* __restrict__ sums, int m)
{
    __shared__ int lds[256];
    int base = blockIdx.x * SCAN_SZ;
    int t = threadIdx.x;
    int v[8]; int s = 0;
    #pragma unroll
    for (int j = 0; j < 8; ++j) {
        int idx = base + t * 8 + j;
        v[j] = (idx < m) ? in[idx] : 0;
        s += v[j];
    }
    lds[t] = s;
    __syncthreads();
    for (int off = 1; off < 256; off <<= 1) {
        int a = (t >= off) ? lds[t - off] : 0;
        __syncthreads();
        lds[t] += a;
        __syncthreads();
    }
    int run = lds[t] - s;
    if (t == 255) sums[blockIdx.x] = lds[t];
    #pragma unroll
    for (int j = 0; j < 8; ++j) {
        int idx = base + t * 8 + j;
        if (idx < m) part[idx] = run;
        run += v[j];
    }
}

// writes scand TRANSPOSED: scandT[chunk*NBUCK + bucket]
__global__ __launch_bounds__(256)
void scan3_kernel(const int* __restrict__ part, const int* __restrict__ sums,
                  int* __restrict__ outT, int* __restrict__ bstart,
                  int m, int NSB, int NBUCK, int E, int nb)
{
    __shared__ int spre[512];
    int i = blockIdx.x * 256 + threadIdx.x;
    if (threadIdx.x == 0) {
        int r = 0;
        for (int j = 0; j < nb; ++j) { spre[j] = r; r += sums[j]; }
    }
    __syncthreads();
    if (i < m) {
        int v = part[i] + spre[i / SCAN_SZ];
        int bucket = i / NSB;
        int chunk  = i - bucket * NSB;
        outT[(size_t)chunk * NBUCK + bucket] = v;
        if (chunk == 0) bstart[bucket] = v;
    }
    if (i == 0) bstart[NBUCK] = E;
}

// ---------------- aggregation: 4 nodes/wave, 2 groups x 8 lanes per node ----
template<int H, int CH, int MODE>
__global__ __launch_bounds__(256)
void aggregate_csr(const int* __restrict__ offs, const unsigned short* __restrict__ ssrc2,
                   const float* __restrict__ asrc, const float* __restrict__ adst,
                   const _Float16* __restrict__ xl, const float* __restrict__ bias,
                   float* __restrict__ outp, int n)
{
    int d = blockIdx.x * 16 + (threadIdx.x >> 4);
    if (d >= n) return;
    int sub = threadIdx.x & 15;
    int g = sub >> 3;           // 0..1 edge group (per quarter-wave)
    int s8 = sub & 7;           // channel octet
    int h = (s8 * 8) / CH;      // L1 (CH=8): h=s8; L2 (CH=16): h=s8>>1

    float ad = adst[(unsigned)d * H + h];
    int beg = offs[d], end = offs[d + 1];

    half2v a01 = {(_Float16)0.f, (_Float16)0.f};
    half2v a23 = a01, a45 = a01, a67 = a01;
    float den = 0.f;

    #pragma unroll 4
    for (int i = beg + g; i < end; i += 2) {
        int s = (int)ssrc2[i];
        float l = asrc[(unsigned)s * H + h] + ad;
        l = fmaxf(l, LEAK * l);            // leaky-relu (logits prescaled)
        float p = fast_exp2(l);
        uint4 hv = *reinterpret_cast<const uint4*>(xl + ((unsigned)s << 6) + 8u * s8);
        den += p;
        half2v ph = pack2(p, p);
        a01 = u2h(hv.x) * ph + a01;        // v_pk_fma_f16
        a23 = u2h(hv.y) * ph + a23;
        a45 = u2h(hv.z) * ph + a45;
        a67 = u2h(hv.w) * ph + a67;
    }

    // convert f16 chains to f32; combine 2 groups (xor 8, within quarter-wave)
    float v8[8];
    v8[0] = (float)a01.x; v8[1] = (float)a01.y;
    v8[2] = (float)a23.x; v8[3] = (float)a23.y;
    v8[4] = (float)a45.x; v8[5] = (float)a45.y;
    v8[6] = (float)a67.x; v8[7] = (float)a67.y;
    #pragma unroll
    for (int j = 0; j < 8; ++j) v8[j] += __shfl_xor(v8[j], 8);
    den += __shfl_xor(den, 8);

    // self-loop (f32, once per node)
    {
        float l = asrc[(unsigned)d * H + h] + ad;
        l = fmaxf(l, LEAK * l);
        float ps = fast_exp2(l);
        uint4 hv = *reinterpret_cast<const uint4*>(xl + ((unsigned)d << 6) + 8u * s8);
        den += ps;
        half2v x01 = u2h(hv.x), x23 = u2h(hv.y), x45 = u2h(hv.z), x67 = u2h(hv.w);
        v8[0] = fmaf(ps, (float)x01.x, v8[0]);
        v8[1] = fmaf(ps, (float)x01.y, v8[1]);
        v8[2] = fmaf(ps, (float)x23.x, v8[2]);
        v8[3] = fmaf(ps, (float)x23.y, v8[3]);
        v8[4] = fmaf(ps, (float)x45.x, v8[4]);
        v8[5] = fmaf(ps, (float)x45.y, v8[5]);
        v8[6] = fmaf(ps, (float)x67.x, v8[6]);
        v8[7] = fmaf(ps, (float)x67.y, v8[7]);
    }
    float inv = 1.f / fmaxf(den, EPSV);
    #pragma unroll
    for (int j = 0; j < 8; ++j) v8[j] *= inv;

    if (MODE == 1) {
        if (g == 0) {   // lanes sub 0..7 of each quarter-wave write their node
            float4 ba = reinterpret_cast<const float4*>(bias)[2 * s8];
            float4 bb = reinterpret_cast<const float4*>(bias)[2 * s8 + 1];
            float o0 = elu_f(v8[0] + ba.x), o1 = elu_f(v8[1] + ba.y);
            float o2 = elu_f(v8[2] + ba.z), o3 = elu_f(v8[3] + ba.w);
            float o4 = elu_f(v8[4] + bb.x), o5 = elu_f(v8[5] + bb.y);
            float o6 = elu_f(v8[6] + bb.z), o7 = elu_f(v8[7] + bb.w);
            float* op = outp + (size_t)d * 64 + 8 * s8;
            *reinterpret_cast<float4*>(op)     = make_float4(o0, o1, o2, o3);
            *reinterpret_cast<float4*>(op + 4) = make_float4(o4, o5, o6, o7);
        }
    } else {
        // head-mean over H=4 (CH=16): xor 2,4 on s8 bits (within quarter-wave)
        #pragma unroll
        for (int j = 0; j < 8; ++j) {
            v8[j] += __shfl_xor(v8[j], 2);
            v8[j] += __shfl_xor(v8[j], 4);
        }
        if (sub < 2) {   // g==0, s8 in {0,1}: out channels 8*s8..8*s8+7
            float4 ba = reinterpret_cast<const float4*>(bias)[2 * s8];
            float4 bb = reinterpret_cast<const float4*>(bias)[2 * s8 + 1];
            float* op = outp + (size_t)d * 16 + 8 * s8;
            *reinterpret_cast<float4*>(op) = make_float4(
                0.25f * v8[0] + ba.x, 0.25f * v8[1] + ba.y,
                0.25f * v8[2] + ba.z, 0.25f * v8[3] + ba.w);
            *reinterpret_cast<float4*>(op + 4) = make_float4(
                0.25f * v8[4] + bb.x, 0.25f * v8[5] + bb.y,
                0.25f * v8[6] + bb.z, 0.25f * v8[7] + bb.w);
        }
    }
}

// ---------------- host ----------------
extern "C" void kernel_launch(void* const* d_in, const int* in_sizes, int n_in,
                              void* d_out, int out_size, void* d_ws, size_t ws_size,
                              hipStream_t stream)
{
    const float* x      = (const float*)d_in[0];
    const int*   ei     = (const int*)d_in[1];
    const float* W1     = (const float*)d_in[2];
    const float* a_src1 = (const float*)d_in[3];
    const float* a_dst1 = (const float*)d_in[4];
    const float* b1     = (const float*)d_in[5];
    const float* W2     = (const float*)d_in[6];
    const float* a_src2 = (const float*)d_in[7];
    const float* a_dst2 = (const float*)d_in[8];
    const float* b2     = (const float*)d_in[9];
    float* out = (float*)d_out;

    const int n = in_sizes[0] / 256;     // 50000
    const int E = in_sizes[1] / 2;       // 1600000
    const int* src = ei;
    const int* dst = ei + E;

    const int NSB   = (E + CHUNK - 1) / CHUNK;        // 782
    const int NBUCK = (n + 63) >> BSH;                // 782
    const int m     = NBUCK * NSB;                    // 611524
    const int nb    = (m + SCAN_SZ - 1) / SCAN_SZ;    // 299
    const int NTB   = (n + 31) / 32;                  // 1563 (32-node tiles)
    const int T1    = NTB / 3;                        // 521
    const int T2    = NTB / 3;                        // 521
    const int T3    = NTB - T1 - T2;                  // 521

    size_t N64 = (size_t)n * 64;
    size_t N8  = (size_t)n * 8;
    _Float16* xlh  = (_Float16*)d_ws;                 // N*64 fp16 (both layers)
    float* hbuf    = (float*)(xlh + N64);             // N*64 f32 (h)
    float* asrc    = hbuf + N64;                      // N*8
    float* adst    = asrc + N8;                       // N*8
    int*   histm   = (int*)(adst + N8);               // m
    int*   part    = histm + m;                       // m
    int*   scandT  = part + m;                        // m (transposed)
    int*   sums    = scandT + m;                      // 512
    int*   bstart  = sums + 512;                      // NBUCK+1 (783)
    int*   offs    = bstart + NBUCK + 1;              // n+1 (50001)
    unsigned* ssrc = (unsigned*)(offs + n + 1);       // E (4B)
    unsigned short* ssrc2 = (unsigned short*)(ssrc + E);   // E (2B)
    (void)ws_size; (void)n_in; (void)out_size;

    // ----- phase A: hist + NT1 tiles [0, T1) -----
    hist_nt<256, 8, 8><<<NSB + T1, 256, 0, stream>>>(
        x, W1, a_src1, a_dst1, xlh, asrc, adst, n, dst, E, histm, NBUCK, NSB, 0);

    // ----- scans (scan3 writes transposed) -----
    scan1_kernel<<<nb, 256, 0, stream>>>(histm, part, sums, m);
    scan3_kernel<<<(m + 255) / 256, 256, 0, stream>>>(part, sums, scandT, bstart,
                                                      m, NSB, NBUCK, E, nb);

    // ----- phase B: sort_place + NT1 tiles [T1, T1+T2) -----
    place_nt<256, 8, 8><<<NSB + T2, 256, 0, stream>>>(
        x, W1, a_src1, a_dst1, xlh, asrc, adst, n,
        src, dst, E, scandT, NBUCK, NSB, ssrc, T1);

    // ----- phase C: bucket_nodesort + NT1 tiles [T1+T2, NTB) -----
    nodesort_nt<256, 8, 8><<<NBUCK + T3, 256, 0, stream>>>(
        x, W1, a_src1, a_dst1, xlh, asrc, adst, n,
        ssrc, bstart, ssrc2, offs, NBUCK, E, T1 + T2);

    // ----- Layer 1 aggregate: 256 -> 8x8, concat, +b1, ELU -----
    aggregate_csr<8, 8, 1><<<(n + 15) / 16, 256, 0, stream>>>(offs, ssrc2, asrc, adst,
                                                              xlh, b1, hbuf, n);

    // ----- Layer 2: 64 -> 4x16, mean heads, +b2 -----
    node_transform<64, 4, 16><<<NTB, 256, 0, stream>>>(
        hbuf, W2, a_src2, a_dst2, xlh, asrc, adst, n);
    aggregate_csr<4, 16, 2><<<(n + 15) / 16, 256, 0, stream>>>(offs, ssrc2, asrc, adst,
                                                               xlh, b2, out, n);
}

// Round 22
// 139.258 us; speedup vs baseline: 1.1347x; 1.1209x over previous
//
#include <hip/hip_runtime.h>
#include <math.h>

// 2-layer GAT (PyG GATConv), N=50000, E=1.6M, IN=256.
// Round 22 = round 21 (156.1us) with ONE change:
//  - CHUNK 2048 -> 8192: sort_place's scatter runs grow 2.6 -> 10.5 entries
//    (42B), cutting write amplification ~50MB -> ~18MB (the measured floor
//    of place_nt: 41.7us at VALUBusy 9.9% = scattered-write-bound). The old
//    big-chunk occupancy problem is gone: fat kernels co-schedule 521 NT
//    tiles with the 196 sort blocks, and per-thread edge iterations are
//    independent (ILP covers the longer loop). Scan shrinks 611K -> 153K.
//  - everything else identical to round 21.

#define LEAK 0.2f
#define EPSV 1e-16f
#define CHUNK 8192           // edges per sort block
#define BSH 6                // bucket shift: 64 nodes per bucket
#define MAXB 1024            // >= NBUCK (782)
#define LOG2E 1.44269504088896340736f

typedef __attribute__((ext_vector_type(4))) _Float16 half4;
typedef __attribute__((ext_vector_type(2))) _Float16 half2v;
typedef __attribute__((ext_vector_type(2))) __fp16 fp16v2;

#if defined(__has_builtin)
#if __has_builtin(__builtin_amdgcn_fdot2)
#define HAVE_FDOT2 1
#endif
#if __has_builtin(__builtin_amdgcn_exp2f)
#define HAVE_EXP2 1
#endif
#if __has_builtin(__builtin_amdgcn_cvt_pkrtz)
#define HAVE_PKRTZ 1
#endif
#endif

__device__ __forceinline__ float fast_exp2(float x) {
#ifdef HAVE_EXP2
    return __builtin_amdgcn_exp2f(x);
#else
    return exp2f(x);
#endif
}

// elu negative branch via exp2; abs err ~1e-7 (threshold 2.7e-3)
__device__ __forceinline__ float elu_f(float v) {
    return (v > 0.f) ? v : (fast_exp2(v * LOG2E) - 1.f);
}

__device__ __forceinline__ half2v pack2(float a, float b) {
#ifdef HAVE_PKRTZ
    union { fp16v2 f; half2v h; } u;
    u.f = __builtin_amdgcn_cvt_pkrtz(a, b);
    return u.h;
#else
    half2v r; r.x = (_Float16)a; r.y = (_Float16)b; return r;
#endif
}

__device__ __forceinline__ half2v u2h(unsigned v) {
    union { unsigned u; half2v h; } c; c.u = v; return c.h;
}

__device__ __forceinline__ float dot2f(unsigned a, unsigned b, float c) {
    union { unsigned u; half2v h; } ua, ub;
    ua.u = a; ub.u = b;
#ifdef HAVE_FDOT2
    return __builtin_amdgcn_fdot2(ua.h, ub.h, c, false);
#else
    return fmaf((float)ua.h.x, (float)ub.h.x,
                fmaf((float)ua.h.y, (float)ub.h.y, c));
#endif
}

// ---------------- node transform body: 32-node tile, fp16-LDS dot2 GEMM ----
template<int K, int H, int CH>
__device__ __forceinline__
void nt_body(unsigned char* smem, int bid,
             const float* __restrict__ x, const float* __restrict__ W,
             const float* __restrict__ a_s, const float* __restrict__ a_d,
             _Float16* __restrict__ xl_out, float* __restrict__ asrc,
             float* __restrict__ adst, int n)
{
    _Float16 (*xsh)[72]  = reinterpret_cast<_Float16(*)[72]>(smem);       // 32r, 4608B
    unsigned (*wskp)[68] = reinterpret_cast<unsigned(*)[68]>(smem + 4608); // 32r, 8704B
    float (*otile)[68]   = reinterpret_cast<float(*)[68]>(smem);          // epilogue

    int tid = threadIdx.x;
    int tx = tid & 15;
    int ty = tid >> 4;
    int nbase = bid * 32;

    float acc[2][4] = {};
    for (int k0 = 0; k0 < K; k0 += 64) {
        __syncthreads();
        #pragma unroll
        for (int rr = 0; rr < 2; ++rr) {
            int r = ty + 16 * rr;
            int node = nbase + r;
            float4 v = make_float4(0.f, 0.f, 0.f, 0.f);
            if (node < n)
                v = *reinterpret_cast<const float4*>(x + (size_t)node * K + k0 + 4 * tx);
            half4 hv;
            hv.x = (_Float16)v.x; hv.y = (_Float16)v.y;
            hv.z = (_Float16)v.z; hv.w = (_Float16)v.w;
            *reinterpret_cast<half4*>(&xsh[r][4 * tx]) = hv;
        }
        #pragma unroll
        for (int rr = 0; rr < 2; ++rr) {
            int kp = ty + 16 * rr;   // 0..31
            const float* w0 = W + (size_t)(k0 + 2 * kp) * 64 + 4 * tx;
            float4 wa = *reinterpret_cast<const float4*>(w0);
            float4 wb = *reinterpret_cast<const float4*>(w0 + 64);
            union { half2v h; unsigned u; } p0, p1, p2, p3;
            p0.h.x = (_Float16)wa.x; p0.h.y = (_Float16)wb.x;
            p1.h.x = (_Float16)wa.y; p1.h.y = (_Float16)wb.y;
            p2.h.x = (_Float16)wa.z; p2.h.y = (_Float16)wb.z;
            p3.h.x = (_Float16)wa.w; p3.h.y = (_Float16)wb.w;
            uint4 pk; pk.x = p0.u; pk.y = p1.u; pk.z = p2.u; pk.w = p3.u;
            *reinterpret_cast<uint4*>(&wskp[kp][4 * tx]) = pk;
        }
        __syncthreads();
        #pragma unroll 2
        for (int k8 = 0; k8 < 8; ++k8) {
            uint4 wf0 = *reinterpret_cast<const uint4*>(&wskp[k8 * 4 + 0][4 * tx]);
            uint4 wf1 = *reinterpret_cast<const uint4*>(&wskp[k8 * 4 + 1][4 * tx]);
            uint4 wf2 = *reinterpret_cast<const uint4*>(&wskp[k8 * 4 + 2][4 * tx]);
            uint4 wf3 = *reinterpret_cast<const uint4*>(&wskp[k8 * 4 + 3][4 * tx]);
            #pragma unroll
            for (int rr = 0; rr < 2; ++rr) {
                uint4 xr = *reinterpret_cast<const uint4*>(&xsh[ty + 16 * rr][k8 * 8]);
                acc[rr][0] = dot2f(xr.x, wf0.x, acc[rr][0]);
                acc[rr][1] = dot2f(xr.x, wf0.y, acc[rr][1]);
                acc[rr][2] = dot2f(xr.x, wf0.z, acc[rr][2]);
                acc[rr][3] = dot2f(xr.x, wf0.w, acc[rr][3]);
                acc[rr][0] = dot2f(xr.y, wf1.x, acc[rr][0]);
                acc[rr][1] = dot2f(xr.y, wf1.y, acc[rr][1]);
                acc[rr][2] = dot2f(xr.y, wf1.z, acc[rr][2]);
                acc[rr][3] = dot2f(xr.y, wf1.w, acc[rr][3]);
                acc[rr][0] = dot2f(xr.z, wf2.x, acc[rr][0]);
                acc[rr][1] = dot2f(xr.z, wf2.y, acc[rr][1]);
                acc[rr][2] = dot2f(xr.z, wf2.z, acc[rr][2]);
                acc[rr][3] = dot2f(xr.z, wf2.w, acc[rr][3]);
                acc[rr][0] = dot2f(xr.w, wf3.x, acc[rr][0]);
                acc[rr][1] = dot2f(xr.w, wf3.y, acc[rr][1]);
                acc[rr][2] = dot2f(xr.w, wf3.z, acc[rr][2]);
                acc[rr][3] = dot2f(xr.w, wf3.w, acc[rr][3]);
            }
        }
    }
    __syncthreads();   // reuse smem as f32 out tile
    #pragma unroll
    for (int rr = 0; rr < 2; ++rr) {
        int r = ty + 16 * rr;
        int node = nbase + r;
        otile[r][4 * tx + 0] = acc[rr][0];
        otile[r][4 * tx + 1] = acc[rr][1];
        otile[r][4 * tx + 2] = acc[rr][2];
        otile[r][4 * tx + 3] = acc[rr][3];
        if (node < n) {
            half4 hv;
            hv.x = (_Float16)acc[rr][0]; hv.y = (_Float16)acc[rr][1];
            hv.z = (_Float16)acc[rr][2]; hv.w = (_Float16)acc[rr][3];
            *reinterpret_cast<half4*>(xl_out + (size_t)node * 64 + 4 * tx) = hv;
        }
    }
    __syncthreads();
    for (int t = tid; t < 32 * H; t += 256) {
        int nl = t / H, h = t - nl * H;
        int node = nbase + nl;
        if (node < n) {
            float s = 0.f, d = 0.f;
            #pragma unroll
            for (int c = 0; c < CH; ++c) {
                float v = otile[nl][h * CH + c];
                s = fmaf(v, a_s[h * CH + c], s);
                d = fmaf(v, a_d[h * CH + c], d);
            }
            asrc[node * H + h] = s * LOG2E;
            adst[node * H + h] = d * LOG2E;
        }
    }
}

// standalone NT kernel (layer 2)
template<int K, int H, int CH>
__global__ __launch_bounds__(256)
void node_transform(const float* __restrict__ x, const float* __restrict__ W,
                    const float* __restrict__ a_s, const float* __restrict__ a_d,
                    _Float16* __restrict__ xl_out, float* __restrict__ asrc,
                    float* __restrict__ adst, int n)
{
    __shared__ __align__(16) unsigned char smem[13312];
    nt_body<K, H, CH>(smem, blockIdx.x, x, W, a_s, a_d, xl_out, asrc, adst, n);
}

// fat 1: blocks [0,NSB) = dst histogram; rest = NT1 tiles
template<int K, int H, int CH>
__global__ __launch_bounds__(256)
void hist_nt(const float* __restrict__ x, const float* __restrict__ W,
             const float* __restrict__ a_s, const float* __restrict__ a_d,
             _Float16* __restrict__ xl_out, float* __restrict__ asrc,
             float* __restrict__ adst, int n,
             const int* __restrict__ dst, int E,
             int* __restrict__ hist_mat, int NBUCK, int NSB, int ntStart)
{
    __shared__ __align__(16) unsigned char smem[13312];
    if ((int)blockIdx.x < NSB) {
        int* h = reinterpret_cast<int*>(smem);
        int tid = threadIdx.x, chunk = blockIdx.x;
        for (int b = tid; b < NBUCK; b += 256) h[b] = 0;
        __syncthreads();
        int base = chunk * CHUNK, end = min(base + CHUNK, E);
        for (int i = base + tid; i < end; i += 256)
            atomicAdd(&h[dst[i] >> BSH], 1);
        __syncthreads();
        for (int b = tid; b < NBUCK; b += 256)
            hist_mat[b * NSB + chunk] = h[b];
    } else {
        nt_body<K, H, CH>(smem, ntStart + (int)blockIdx.x - NSB,
                          x, W, a_s, a_d, xl_out, asrc, adst, n);
    }
}

// fat 2: blocks [0,NSB) = sort_place (cursor init from TRANSPOSED scand);
// rest = NT1 tiles
template<int K, int H, int CH>
__global__ __launch_bounds__(256)
void place_nt(const float* __restrict__ x, const float* __restrict__ W,
              const float* __restrict__ a_s, const float* __restrict__ a_d,
              _Float16* __restrict__ xl_out, float* __restrict__ asrc,
              float* __restrict__ adst, int n,
              const int* __restrict__ src, const int* __restrict__ dst, int E,
              const int* __restrict__ scandT, int NBUCK, int NSB,
              unsigned* __restrict__ ssrc, int ntStart)
{
    __shared__ __align__(16) unsigned char smem[13312];
    if ((int)blockIdx.x < NSB) {
        int* cur = reinterpret_cast<int*>(smem);
        int tid = threadIdx.x, chunk = blockIdx.x;
        for (int b = tid; b < NBUCK; b += 256)
            cur[b] = scandT[(size_t)chunk * NBUCK + b];    // coalesced
        __syncthreads();
        int base = chunk * CHUNK, end = min(base + CHUNK, E);
        for (int i = base + tid; i < end; i += 256) {
            int d = dst[i];
            int b = d >> BSH;
            int slot = atomicAdd(&cur[b], 1);
            ssrc[slot] = ((unsigned)src[i] << BSH) | (unsigned)(d & 63);
        }
    } else {
        nt_body<K, H, CH>(smem, ntStart + (int)blockIdx.x - NSB,
                          x, W, a_s, a_d, xl_out, asrc, adst, n);
    }
}

// fat 3: blocks [0,NBUCK) = bucket_nodesort; rest = NT1 tiles
template<int K, int H, int CH>
__global__ __launch_bounds__(256)
void nodesort_nt(const float* __restrict__ x, const float* __restrict__ W,
                 const float* __restrict__ a_s, const float* __restrict__ a_d,
                 _Float16* __restrict__ xl_out, float* __restrict__ asrc,
                 float* __restrict__ adst, int n,
                 const unsigned* __restrict__ ssrc, const int* __restrict__ bstart,
                 unsigned short* __restrict__ ssrc2, int* __restrict__ offs,
                 int NBUCK, int E, int ntStart)
{
    __shared__ __align__(16) unsigned char smem[13312];
    if ((int)blockIdx.x < NBUCK) {
        int* cnt  = reinterpret_cast<int*>(smem);          // 64
        int* base_ = cnt + 64;                             // 64
        int bk = blockIdx.x, tid = threadIdx.x;
        int beg = bstart[bk], end = bstart[bk + 1];
        if (tid < 64) cnt[tid] = 0;
        __syncthreads();
        for (int i = beg + tid; i < end; i += 256)
            atomicAdd(&cnt[ssrc[i] & 63], 1);
        __syncthreads();
        if (tid == 0) {
            int r = 0;
            for (int j = 0; j < 64; ++j) { int c = cnt[j]; base_[j] = r; r += c; }
        }
        __syncthreads();
        if (tid < 64) {
            int node = (bk << BSH) + tid;
            if (node < n) offs[node] = beg + base_[tid];
            cnt[tid] = 0;    // reuse as cursor
        }
        __syncthreads();
        for (int i = beg + tid; i < end; i += 256) {
            unsigned e = ssrc[i];
            int dl = e & 63;
            int r = atomicAdd(&cnt[dl], 1);
            ssrc2[beg + base_[dl] + r] = (unsigned short)(e >> BSH);
        }
        if (bk == 0 && tid == 0) offs[n] = E;
    } else {
        nt_body<K, H, CH>(smem, ntStart + (int)blockIdx.x - NBUCK,
                          x, W, a_s, a_d, xl_out, asrc, adst, n);
    }
}

#define SCAN_SZ 2048
__global__ __launch_bounds__(256)
void scan1_kernel(const int* __restrict__ in, int* __restrict__ part,
                  int* __restrict__ sums, int m)
{
    __shared__ int lds[256];
    int base = blockIdx.x * SCAN_SZ;
    int t = threadIdx.x;
    int v[8]; int s = 0;
    #pragma unroll
    for (int j = 0; j < 8; ++j) {
        int idx = base + t * 8 + j;
        v[j] = (idx < m) ? in[idx] : 0;
        s += v[j];
    }
    lds[t] = s;
    __syncthreads();
    for (int off = 1; off < 256; off <<= 1) {
        int a = (t >= off) ? lds[t - off] : 0;
        __syncthreads();
        lds[t] += a;
        __syncthreads();
    }
    int run = lds[t] - s;
    if (t == 255) sums[blockIdx.x] = lds[t];
    #pragma unroll
    for (int j = 0; j < 8; ++j) {
        int idx = base + t * 8 + j;
        if (idx < m) part[idx] = run;
        run += v[j];
    }
}

// writes scand TRANSPOSED: scandT[chunk*NBUCK + bucket]
__global__ __launch_bounds__(256)
void scan3_kernel(const int* __restrict__ part, const int* __restrict__ sums,
                  int* __restrict__ outT, int* __restrict__ bstart,
                  int m, int NSB, int NBUCK, int E, int nb)
{
    __shared__ int spre[512];
    int i = blockIdx.x * 256 + threadIdx.x;
    if (threadIdx.x == 0) {
        int r = 0;
        for (int j = 0; j < nb; ++j) { spre[j] = r; r += sums[j]; }
    }
    __syncthreads();
    if (i < m) {
        int v = part[i] + spre[i / SCAN_SZ];
        int bucket = i / NSB;
        int chunk  = i - bucket * NSB;
        outT[(size_t)chunk * NBUCK + bucket] = v;
        if (chunk == 0) bstart[bucket] = v;
    }
    if (i == 0) bstart[NBUCK] = E;
}

// ---------------- aggregation: 4 nodes/wave, 2 groups x 8 lanes per node ----
template<int H, int CH, int MODE>
__global__ __launch_bounds__(256)
void aggregate_csr(const int* __restrict__ offs, const unsigned short* __restrict__ ssrc2,
                   const float* __restrict__ asrc, const float* __restrict__ adst,
                   const _Float16* __restrict__ xl, const float* __restrict__ bias,
                   float* __restrict__ outp, int n)
{
    int d = blockIdx.x * 16 + (threadIdx.x >> 4);
    if (d >= n) return;
    int sub = threadIdx.x & 15;
    int g = sub >> 3;           // 0..1 edge group (per quarter-wave)
    int s8 = sub & 7;           // channel octet
    int h = (s8 * 8) / CH;      // L1 (CH=8): h=s8; L2 (CH=16): h=s8>>1

    float ad = adst[(unsigned)d * H + h];
    int beg = offs[d], end = offs[d + 1];

    half2v a01 = {(_Float16)0.f, (_Float16)0.f};
    half2v a23 = a01, a45 = a01, a67 = a01;
    float den = 0.f;

    #pragma unroll 4
    for (int i = beg + g; i < end; i += 2) {
        int s = (int)ssrc2[i];
        float l = asrc[(unsigned)s * H + h] + ad;
        l = fmaxf(l, LEAK * l);            // leaky-relu (logits prescaled)
        float p = fast_exp2(l);
        uint4 hv = *reinterpret_cast<const uint4*>(xl + ((unsigned)s << 6) + 8u * s8);
        den += p;
        half2v ph = pack2(p, p);
        a01 = u2h(hv.x) * ph + a01;        // v_pk_fma_f16
        a23 = u2h(hv.y) * ph + a23;
        a45 = u2h(hv.z) * ph + a45;
        a67 = u2h(hv.w) * ph + a67;
    }

    // convert f16 chains to f32; combine 2 groups (xor 8, within quarter-wave)
    float v8[8];
    v8[0] = (float)a01.x; v8[1] = (float)a01.y;
    v8[2] = (float)a23.x; v8[3] = (float)a23.y;
    v8[4] = (float)a45.x; v8[5] = (float)a45.y;
    v8[6] = (float)a67.x; v8[7] = (float)a67.y;
    #pragma unroll
    for (int j = 0; j < 8; ++j) v8[j] += __shfl_xor(v8[j], 8);
    den += __shfl_xor(den, 8);

    // self-loop (f32, once per node)
    {
        float l = asrc[(unsigned)d * H + h] + ad;
        l = fmaxf(l, LEAK * l);
        float ps = fast_exp2(l);
        uint4 hv = *reinterpret_cast<const uint4*>(xl + ((unsigned)d << 6) + 8u * s8);
        den += ps;
        half2v x01 = u2h(hv.x), x23 = u2h(hv.y), x45 = u2h(hv.z), x67 = u2h(hv.w);
        v8[0] = fmaf(ps, (float)x01.x, v8[0]);
        v8[1] = fmaf(ps, (float)x01.y, v8[1]);
        v8[2] = fmaf(ps, (float)x23.x, v8[2]);
        v8[3] = fmaf(ps, (float)x23.y, v8[3]);
        v8[4] = fmaf(ps, (float)x45.x, v8[4]);
        v8[5] = fmaf(ps, (float)x45.y, v8[5]);
        v8[6] = fmaf(ps, (float)x67.x, v8[6]);
        v8[7] = fmaf(ps, (float)x67.y, v8[7]);
    }
    float inv = 1.f / fmaxf(den, EPSV);
    #pragma unroll
    for (int j = 0; j < 8; ++j) v8[j] *= inv;

    if (MODE == 1) {
        if (g == 0) {   // lanes sub 0..7 of each quarter-wave write their node
            float4 ba = reinterpret_cast<const float4*>(bias)[2 * s8];
            float4 bb = reinterpret_cast<const float4*>(bias)[2 * s8 + 1];
            float o0 = elu_f(v8[0] + ba.x), o1 = elu_f(v8[1] + ba.y);
            float o2 = elu_f(v8[2] + ba.z), o3 = elu_f(v8[3] + ba.w);
            float o4 = elu_f(v8[4] + bb.x), o5 = elu_f(v8[5] + bb.y);
            float o6 = elu_f(v8[6] + bb.z), o7 = elu_f(v8[7] + bb.w);
            float* op = outp + (size_t)d * 64 + 8 * s8;
            *reinterpret_cast<float4*>(op)     = make_float4(o0, o1, o2, o3);
            *reinterpret_cast<float4*>(op + 4) = make_float4(o4, o5, o6, o7);
        }
    } else {
        // head-mean over H=4 (CH=16): xor 2,4 on s8 bits (within quarter-wave)
        #pragma unroll
        for (int j = 0; j < 8; ++j) {
            v8[j] += __shfl_xor(v8[j], 2);
            v8[j] += __shfl_xor(v8[j], 4);
        }
        if (sub < 2) {   // g==0, s8 in {0,1}: out channels 8*s8..8*s8+7
            float4 ba = reinterpret_cast<const float4*>(bias)[2 * s8];
            float4 bb = reinterpret_cast<const float4*>(bias)[2 * s8 + 1];
            float* op = outp + (size_t)d * 16 + 8 * s8;
            *reinterpret_cast<float4*>(op) = make_float4(
                0.25f * v8[0] + ba.x, 0.25f * v8[1] + ba.y,
                0.25f * v8[2] + ba.z, 0.25f * v8[3] + ba.w);
            *reinterpret_cast<float4*>(op + 4) = make_float4(
                0.25f * v8[4] + bb.x, 0.25f * v8[5] + bb.y,
                0.25f * v8[6] + bb.z, 0.25f * v8[7] + bb.w);
        }
    }
}

// ---------------- host ----------------
extern "C" void kernel_launch(void* const* d_in, const int* in_sizes, int n_in,
                              void* d_out, int out_size, void* d_ws, size_t ws_size,
                              hipStream_t stream)
{
    const float* x      = (const float*)d_in[0];
    const int*   ei     = (const int*)d_in[1];
    const float* W1     = (const float*)d_in[2];
    const float* a_src1 = (const float*)d_in[3];
    const float* a_dst1 = (const float*)d_in[4];
    const float* b1     = (const float*)d_in[5];
    const float* W2     = (const float*)d_in[6];
    const float* a_src2 = (const float*)d_in[7];
    const float* a_dst2 = (const float*)d_in[8];
    const float* b2     = (const float*)d_in[9];
    float* out = (float*)d_out;

    const int n = in_sizes[0] / 256;     // 50000
    const int E = in_sizes[1] / 2;       // 1600000
    const int* src = ei;
    const int* dst = ei + E;

    const int NSB   = (E + CHUNK - 1) / CHUNK;        // 196
    const int NBUCK = (n + 63) >> BSH;                // 782
    const int m     = NBUCK * NSB;                    // 153272
    const int nb    = (m + SCAN_SZ - 1) / SCAN_SZ;    // 75
    const int NTB   = (n + 31) / 32;                  // 1563 (32-node tiles)
    const int T1    = NTB / 3;                        // 521
    const int T2    = NTB / 3;                        // 521
    const int T3    = NTB - T1 - T2;                  // 521

    size_t N64 = (size_t)n * 64;
    size_t N8  = (size_t)n * 8;
    _Float16* xlh  = (_Float16*)d_ws;                 // N*64 fp16 (both layers)
    float* hbuf    = (float*)(xlh + N64);             // N*64 f32 (h)
    float* asrc    = hbuf + N64;                      // N*8
    float* adst    = asrc + N8;                       // N*8
    int*   histm   = (int*)(adst + N8);               // m
    int*   part    = histm + m;                       // m
    int*   scandT  = part + m;                        // m (transposed)
    int*   sums    = scandT + m;                      // 512
    int*   bstart  = sums + 512;                      // NBUCK+1 (783)
    int*   offs    = bstart + NBUCK + 1;              // n+1 (50001)
    unsigned* ssrc = (unsigned*)(offs + n + 1);       // E (4B)
    unsigned short* ssrc2 = (unsigned short*)(ssrc + E);   // E (2B)
    (void)ws_size; (void)n_in; (void)out_size;

    // ----- phase A: hist + NT1 tiles [0, T1) -----
    hist_nt<256, 8, 8><<<NSB + T1, 256, 0, stream>>>(
        x, W1, a_src1, a_dst1, xlh, asrc, adst, n, dst, E, histm, NBUCK, NSB, 0);

    // ----- scans (scan3 writes transposed) -----
    scan1_kernel<<<nb, 256, 0, stream>>>(histm, part, sums, m);
    scan3_kernel<<<(m + 255) / 256, 256, 0, stream>>>(part, sums, scandT, bstart,
                                                      m, NSB, NBUCK, E, nb);

    // ----- phase B: sort_place + NT1 tiles [T1, T1+T2) -----
    place_nt<256, 8, 8><<<NSB + T2, 256, 0, stream>>>(
        x, W1, a_src1, a_dst1, xlh, asrc, adst, n,
        src, dst, E, scandT, NBUCK, NSB, ssrc, T1);

    // ----- phase C: bucket_nodesort + NT1 tiles [T1+T2, NTB) -----
    nodesort_nt<256, 8, 8><<<NBUCK + T3, 256, 0, stream>>>(
        x, W1, a_src1, a_dst1, xlh, asrc, adst, n,
        ssrc, bstart, ssrc2, offs, NBUCK, E, T1 + T2);

    // ----- Layer 1 aggregate: 256 -> 8x8, concat, +b1, ELU -----
    aggregate_csr<8, 8, 1><<<(n + 15) / 16, 256, 0, stream>>>(offs, ssrc2, asrc, adst,
                                                              xlh, b1, hbuf, n);

    // ----- Layer 2: 64 -> 4x16, mean heads, +b2 -----
    node_transform<64, 4, 16><<<NTB, 256, 0, stream>>>(
        hbuf, W2, a_src2, a_dst2, xlh, asrc, adst, n);
    aggregate_csr<4, 16, 2><<<(n + 15) / 16, 256, 0, stream>>>(offs, ssrc2, asrc, adst,
                                                               xlh, b2, out, n);
}

// Round 23
// 129.955 us; speedup vs baseline: 1.2159x; 1.0716x over previous
//
#include <hip/hip_runtime.h>
#include <math.h>

// 2-layer GAT (PyG GATConv), N=50000, E=1.6M, IN=256.
// Round 23 = round 22 (139.3us) with TWO changes:
//  - NT tile split rebalanced toward place phase (T1=280, T2=1020, T3=263):
//    r22 showed place_nt at 12% occupancy after its 521 tiles drained
//    (196 sort blocks alone = 0.77 blocks/CU). Now the scatter's full
//    duration is covered by co-resident GEMM waves.
//  - #pragma unroll 4 on place/hist edge loops (independent iterations ->
//    4x per-thread MLP for the low-occupancy tail).
//  - everything else identical to round 22 (CHUNK=8192, transposed scand).

#define LEAK 0.2f
#define EPSV 1e-16f
#define CHUNK 8192           // edges per sort block
#define BSH 6                // bucket shift: 64 nodes per bucket
#define MAXB 1024            // >= NBUCK (782)
#define LOG2E 1.44269504088896340736f

typedef __attribute__((ext_vector_type(4))) _Float16 half4;
typedef __attribute__((ext_vector_type(2))) _Float16 half2v;
typedef __attribute__((ext_vector_type(2))) __fp16 fp16v2;

#if defined(__has_builtin)
#if __has_builtin(__builtin_amdgcn_fdot2)
#define HAVE_FDOT2 1
#endif
#if __has_builtin(__builtin_amdgcn_exp2f)
#define HAVE_EXP2 1
#endif
#if __has_builtin(__builtin_amdgcn_cvt_pkrtz)
#define HAVE_PKRTZ 1
#endif
#endif

__device__ __forceinline__ float fast_exp2(float x) {
#ifdef HAVE_EXP2
    return __builtin_amdgcn_exp2f(x);
#else
    return exp2f(x);
#endif
}

// elu negative branch via exp2; abs err ~1e-7 (threshold 2.7e-3)
__device__ __forceinline__ float elu_f(float v) {
    return (v > 0.f) ? v : (fast_exp2(v * LOG2E) - 1.f);
}

__device__ __forceinline__ half2v pack2(float a, float b) {
#ifdef HAVE_PKRTZ
    union { fp16v2 f; half2v h; } u;
    u.f = __builtin_amdgcn_cvt_pkrtz(a, b);
    return u.h;
#else
    half2v r; r.x = (_Float16)a; r.y = (_Float16)b; return r;
#endif
}

__device__ __forceinline__ half2v u2h(unsigned v) {
    union { unsigned u; half2v h; } c; c.u = v; return c.h;
}

__device__ __forceinline__ float dot2f(unsigned a, unsigned b, float c) {
    union { unsigned u; half2v h; } ua, ub;
    ua.u = a; ub.u = b;
#ifdef HAVE_FDOT2
    return __builtin_amdgcn_fdot2(ua.h, ub.h, c, false);
#else
    return fmaf((float)ua.h.x, (float)ub.h.x,
                fmaf((float)ua.h.y, (float)ub.h.y, c));
#endif
}

// ---------------- node transform body: 32-node tile, fp16-LDS dot2 GEMM ----
template<int K, int H, int CH>
__device__ __forceinline__
void nt_body(unsigned char* smem, int bid,
             const float* __restrict__ x, const float* __restrict__ W,
             const float* __restrict__ a_s, const float* __restrict__ a_d,
             _Float16* __restrict__ xl_out, float* __restrict__ asrc,
             float* __restrict__ adst, int n)
{
    _Float16 (*xsh)[72]  = reinterpret_cast<_Float16(*)[72]>(smem);       // 32r, 4608B
    unsigned (*wskp)[68] = reinterpret_cast<unsigned(*)[68]>(smem + 4608); // 32r, 8704B
    float (*otile)[68]   = reinterpret_cast<float(*)[68]>(smem);          // epilogue

    int tid = threadIdx.x;
    int tx = tid & 15;
    int ty = tid >> 4;
    int nbase = bid * 32;

    float acc[2][4] = {};
    for (int k0 = 0; k0 < K; k0 += 64) {
        __syncthreads();
        #pragma unroll
        for (int rr = 0; rr < 2; ++rr) {
            int r = ty + 16 * rr;
            int node = nbase + r;
            float4 v = make_float4(0.f, 0.f, 0.f, 0.f);
            if (node < n)
                v = *reinterpret_cast<const float4*>(x + (size_t)node * K + k0 + 4 * tx);
            half4 hv;
            hv.x = (_Float16)v.x; hv.y = (_Float16)v.y;
            hv.z = (_Float16)v.z; hv.w = (_Float16)v.w;
            *reinterpret_cast<half4*>(&xsh[r][4 * tx]) = hv;
        }
        #pragma unroll
        for (int rr = 0; rr < 2; ++rr) {
            int kp = ty + 16 * rr;   // 0..31
            const float* w0 = W + (size_t)(k0 + 2 * kp) * 64 + 4 * tx;
            float4 wa = *reinterpret_cast<const float4*>(w0);
            float4 wb = *reinterpret_cast<const float4*>(w0 + 64);
            union { half2v h; unsigned u; } p0, p1, p2, p3;
            p0.h.x = (_Float16)wa.x; p0.h.y = (_Float16)wb.x;
            p1.h.x = (_Float16)wa.y; p1.h.y = (_Float16)wb.y;
            p2.h.x = (_Float16)wa.z; p2.h.y = (_Float16)wb.z;
            p3.h.x = (_Float16)wa.w; p3.h.y = (_Float16)wb.w;
            uint4 pk; pk.x = p0.u; pk.y = p1.u; pk.z = p2.u; pk.w = p3.u;
            *reinterpret_cast<uint4*>(&wskp[kp][4 * tx]) = pk;
        }
        __syncthreads();
        #pragma unroll 2
        for (int k8 = 0; k8 < 8; ++k8) {
            uint4 wf0 = *reinterpret_cast<const uint4*>(&wskp[k8 * 4 + 0][4 * tx]);
            uint4 wf1 = *reinterpret_cast<const uint4*>(&wskp[k8 * 4 + 1][4 * tx]);
            uint4 wf2 = *reinterpret_cast<const uint4*>(&wskp[k8 * 4 + 2][4 * tx]);
            uint4 wf3 = *reinterpret_cast<const uint4*>(&wskp[k8 * 4 + 3][4 * tx]);
            #pragma unroll
            for (int rr = 0; rr < 2; ++rr) {
                uint4 xr = *reinterpret_cast<const uint4*>(&xsh[ty + 16 * rr][k8 * 8]);
                acc[rr][0] = dot2f(xr.x, wf0.x, acc[rr][0]);
                acc[rr][1] = dot2f(xr.x, wf0.y, acc[rr][1]);
                acc[rr][2] = dot2f(xr.x, wf0.z, acc[rr][2]);
                acc[rr][3] = dot2f(xr.x, wf0.w, acc[rr][3]);
                acc[rr][0] = dot2f(xr.y, wf1.x, acc[rr][0]);
                acc[rr][1] = dot2f(xr.y, wf1.y, acc[rr][1]);
                acc[rr][2] = dot2f(xr.y, wf1.z, acc[rr][2]);
                acc[rr][3] = dot2f(xr.y, wf1.w, acc[rr][3]);
                acc[rr][0] = dot2f(xr.z, wf2.x, acc[rr][0]);
                acc[rr][1] = dot2f(xr.z, wf2.y, acc[rr][1]);
                acc[rr][2] = dot2f(xr.z, wf2.z, acc[rr][2]);
                acc[rr][3] = dot2f(xr.z, wf2.w, acc[rr][3]);
                acc[rr][0] = dot2f(xr.w, wf3.x, acc[rr][0]);
                acc[rr][1] = dot2f(xr.w, wf3.y, acc[rr][1]);
                acc[rr][2] = dot2f(xr.w, wf3.z, acc[rr][2]);
                acc[rr][3] = dot2f(xr.w, wf3.w, acc[rr][3]);
            }
        }
    }
    __syncthreads();   // reuse smem as f32 out tile
    #pragma unroll
    for (int rr = 0; rr < 2; ++rr) {
        int r = ty + 16 * rr;
        int node = nbase + r;
        otile[r][4 * tx + 0] = acc[rr][0];
        otile[r][4 * tx + 1] = acc[rr][1];
        otile[r][4 * tx + 2] = acc[rr][2];
        otile[r][4 * tx + 3] = acc[rr][3];
        if (node < n) {
            half4 hv;
            hv.x = (_Float16)acc[rr][0]; hv.y = (_Float16)acc[rr][1];
            hv.z = (_Float16)acc[rr][2]; hv.w = (_Float16)acc[rr][3];
            *reinterpret_cast<half4*>(xl_out + (size_t)node * 64 + 4 * tx) = hv;
        }
    }
    __syncthreads();
    for (int t = tid; t < 32 * H; t += 256) {
        int nl = t / H, h = t - nl * H;
        int node = nbase + nl;
        if (node < n) {
            float s = 0.f, d = 0.f;
            #pragma unroll
            for (int c = 0; c < CH; ++c) {
                float v = otile[nl][h * CH + c];
                s = fmaf(v, a_s[h * CH + c], s);
                d = fmaf(v, a_d[h * CH + c], d);
            }
            asrc[node * H + h] = s * LOG2E;
            adst[node * H + h] = d * LOG2E;
        }
    }
}

// standalone NT kernel (layer 2)
template<int K, int H, int CH>
__global__ __launch_bounds__(256)
void node_transform(const float* __restrict__ x, const float* __restrict__ W,
                    const float* __restrict__ a_s, const float* __restrict__ a_d,
                    _Float16* __restrict__ xl_out, float* __restrict__ asrc,
                    float* __restrict__ adst, int n)
{
    __shared__ __align__(16) unsigned char smem[13312];
    nt_body<K, H, CH>(smem, blockIdx.x, x, W, a_s, a_d, xl_out, asrc, adst, n);
}

// fat 1: blocks [0,NSB) = dst histogram; rest = NT1 tiles
template<int K, int H, int CH>
__global__ __launch_bounds__(256)
void hist_nt(const float* __restrict__ x, const float* __restrict__ W,
             const float* __restrict__ a_s, const float* __restrict__ a_d,
             _Float16* __restrict__ xl_out, float* __restrict__ asrc,
             float* __restrict__ adst, int n,
             const int* __restrict__ dst, int E,
             int* __restrict__ hist_mat, int NBUCK, int NSB, int ntStart)
{
    __shared__ __align__(16) unsigned char smem[13312];
    if ((int)blockIdx.x < NSB) {
        int* h = reinterpret_cast<int*>(smem);
        int tid = threadIdx.x, chunk = blockIdx.x;
        for (int b = tid; b < NBUCK; b += 256) h[b] = 0;
        __syncthreads();
        int base = chunk * CHUNK, end = min(base + CHUNK, E);
        #pragma unroll 4
        for (int i = base + tid; i < end; i += 256)
            atomicAdd(&h[dst[i] >> BSH], 1);
        __syncthreads();
        for (int b = tid; b < NBUCK; b += 256)
            hist_mat[b * NSB + chunk] = h[b];
    } else {
        nt_body<K, H, CH>(smem, ntStart + (int)blockIdx.x - NSB,
                          x, W, a_s, a_d, xl_out, asrc, adst, n);
    }
}

// fat 2: blocks [0,NSB) = sort_place (cursor from transposed scand);
// rest = NT1 tiles
template<int K, int H, int CH>
__global__ __launch_bounds__(256)
void place_nt(const float* __restrict__ x, const float* __restrict__ W,
              const float* __restrict__ a_s, const float* __restrict__ a_d,
              _Float16* __restrict__ xl_out, float* __restrict__ asrc,
              float* __restrict__ adst, int n,
              const int* __restrict__ src, const int* __restrict__ dst, int E,
              const int* __restrict__ scandT, int NBUCK, int NSB,
              unsigned* __restrict__ ssrc, int ntStart)
{
    __shared__ __align__(16) unsigned char smem[13312];
    if ((int)blockIdx.x < NSB) {
        int* cur = reinterpret_cast<int*>(smem);
        int tid = threadIdx.x, chunk = blockIdx.x;
        for (int b = tid; b < NBUCK; b += 256)
            cur[b] = scandT[(size_t)chunk * NBUCK + b];    // coalesced
        __syncthreads();
        int base = chunk * CHUNK, end = min(base + CHUNK, E);
        #pragma unroll 4
        for (int i = base + tid; i < end; i += 256) {
            int d = dst[i];
            int b = d >> BSH;
            int slot = atomicAdd(&cur[b], 1);
            ssrc[slot] = ((unsigned)src[i] << BSH) | (unsigned)(d & 63);
        }
    } else {
        nt_body<K, H, CH>(smem, ntStart + (int)blockIdx.x - NSB,
                          x, W, a_s, a_d, xl_out, asrc, adst, n);
    }
}

// fat 3: blocks [0,NBUCK) = bucket_nodesort; rest = NT1 tiles
template<int K, int H, int CH>
__global__ __launch_bounds__(256)
void nodesort_nt(const float* __restrict__ x, const float* __restrict__ W,
                 const float* __restrict__ a_s, const float* __restrict__ a_d,
                 _Float16* __restrict__ xl_out, float* __restrict__ asrc,
                 float* __restrict__ adst, int n,
                 const unsigned* __restrict__ ssrc, const int* __restrict__ bstart,
                 unsigned short* __restrict__ ssrc2, int* __restrict__ offs,
                 int NBUCK, int E, int ntStart)
{
    __shared__ __align__(16) unsigned char smem[13312];
    if ((int)blockIdx.x < NBUCK) {
        int* cnt  = reinterpret_cast<int*>(smem);          // 64
        int* base_ = cnt + 64;                             // 64
        int bk = blockIdx.x, tid = threadIdx.x;
        int beg = bstart[bk], end = bstart[bk + 1];
        if (tid < 64) cnt[tid] = 0;
        __syncthreads();
        for (int i = beg + tid; i < end; i += 256)
            atomicAdd(&cnt[ssrc[i] & 63], 1);
        __syncthreads();
        if (tid == 0) {
            int r = 0;
            for (int j = 0; j < 64; ++j) { int c = cnt[j]; base_[j] = r; r += c; }
        }
        __syncthreads();
        if (tid < 64) {
            int node = (bk << BSH) + tid;
            if (node < n) offs[node] = beg + base_[tid];
            cnt[tid] = 0;    // reuse as cursor
        }
        __syncthreads();
        #pragma unroll 2
        for (int i = beg + tid; i < end; i += 256) {
            unsigned e = ssrc[i];
            int dl = e & 63;
            int r = atomicAdd(&cnt[dl], 1);
            ssrc2[beg + base_[dl] + r] = (unsigned short)(e >> BSH);
        }
        if (bk == 0 && tid == 0) offs[n] = E;
    } else {
        nt_body<K, H, CH>(smem, ntStart + (int)blockIdx.x - NBUCK,
                          x, W, a_s, a_d, xl_out, asrc, adst, n);
    }
}

#define SCAN_SZ 2048
__global__ __launch_bounds__(256)
void scan1_kernel(const int* __restrict__ in, int* __restrict__ part,
                  int* __restrict__ sums, int m)
{
    __shared__ int lds[256];
    int base = blockIdx.x * SCAN_SZ;
    int t = threadIdx.x;
    int v[8]; int s = 0;
    #pragma unroll
    for (int j = 0; j < 8; ++j) {
        int idx = base + t * 8 + j;
        v[j] = (idx < m) ? in[idx] : 0;
        s += v[j];
    }
    lds[t] = s;
    __syncthreads();
    for (int off = 1; off < 256; off <<= 1) {
        int a = (t >= off) ? lds[t - off] : 0;
        __syncthreads();
        lds[t] += a;
        __syncthreads();
    }
    int run = lds[t] - s;
    if (t == 255) sums[blockIdx.x] = lds[t];
    #pragma unroll
    for (int j = 0; j < 8; ++j) {
        int idx = base + t * 8 + j;
        if (idx < m) part[idx] = run;
        run += v[j];
    }
}

// writes scand TRANSPOSED: scandT[chunk*NBUCK + bucket]
__global__ __launch_bounds__(256)
void scan3_kernel(const int* __restrict__ part, const int* __restrict__ sums,
                  int* __restrict__ outT, int* __restrict__ bstart,
                  int m, int NSB, int NBUCK, int E, int nb)
{
    __shared__ int spre[512];
    int i = blockIdx.x * 256 + threadIdx.x;
    if (threadIdx.x == 0) {
        int r = 0;
        for (int j = 0; j < nb; ++j) { spre[j] = r; r += sums[j]; }
    }
    __syncthreads();
    if (i < m) {
        int v = part[i] + spre[i / SCAN_SZ];
        int bucket = i / NSB;
        int chunk  = i - bucket * NSB;
        outT[(size_t)chunk * NBUCK + bucket] = v;
        if (chunk == 0) bstart[bucket] = v;
    }
    if (i == 0) bstart[NBUCK] = E;
}

// ---------------- aggregation: 4 nodes/wave, 2 groups x 8 lanes per node ----
template<int H, int CH, int MODE>
__global__ __launch_bounds__(256)
void aggregate_csr(const int* __restrict__ offs, const unsigned short* __restrict__ ssrc2,
                   const float* __restrict__ asrc, const float* __restrict__ adst,
                   const _Float16* __restrict__ xl, const float* __restrict__ bias,
                   float* __restrict__ outp, int n)
{
    int d = blockIdx.x * 16 + (threadIdx.x >> 4);
    if (d >= n) return;
    int sub = threadIdx.x & 15;
    int g = sub >> 3;           // 0..1 edge group (per quarter-wave)
    int s8 = sub & 7;           // channel octet
    int h = (s8 * 8) / CH;      // L1 (CH=8): h=s8; L2 (CH=16): h=s8>>1

    float ad = adst[(unsigned)d * H + h];
    int beg = offs[d], end = offs[d + 1];

    half2v a01 = {(_Float16)0.f, (_Float16)0.f};
    half2v a23 = a01, a45 = a01, a67 = a01;
    float den = 0.f;

    #pragma unroll 4
    for (int i = beg + g; i < end; i += 2) {
        int s = (int)ssrc2[i];
        float l = asrc[(unsigned)s * H + h] + ad;
        l = fmaxf(l, LEAK * l);            // leaky-relu (logits prescaled)
        float p = fast_exp2(l);
        uint4 hv = *reinterpret_cast<const uint4*>(xl + ((unsigned)s << 6) + 8u * s8);
        den += p;
        half2v ph = pack2(p, p);
        a01 = u2h(hv.x) * ph + a01;        // v_pk_fma_f16
        a23 = u2h(hv.y) * ph + a23;
        a45 = u2h(hv.z) * ph + a45;
        a67 = u2h(hv.w) * ph + a67;
    }

    // convert f16 chains to f32; combine 2 groups (xor 8, within quarter-wave)
    float v8[8];
    v8[0] = (float)a01.x; v8[1] = (float)a01.y;
    v8[2] = (float)a23.x; v8[3] = (float)a23.y;
    v8[4] = (float)a45.x; v8[5] = (float)a45.y;
    v8[6] = (float)a67.x; v8[7] = (float)a67.y;
    #pragma unroll
    for (int j = 0; j < 8; ++j) v8[j] += __shfl_xor(v8[j], 8);
    den += __shfl_xor(den, 8);

    // self-loop (f32, once per node)
    {
        float l = asrc[(unsigned)d * H + h] + ad;
        l = fmaxf(l, LEAK * l);
        float ps = fast_exp2(l);
        uint4 hv = *reinterpret_cast<const uint4*>(xl + ((unsigned)d << 6) + 8u * s8);
        den += ps;
        half2v x01 = u2h(hv.x), x23 = u2h(hv.y), x45 = u2h(hv.z), x67 = u2h(hv.w);
        v8[0] = fmaf(ps, (float)x01.x, v8[0]);
        v8[1] = fmaf(ps, (float)x01.y, v8[1]);
        v8[2] = fmaf(ps, (float)x23.x, v8[2]);
        v8[3] = fmaf(ps, (float)x23.y, v8[3]);
        v8[4] = fmaf(ps, (float)x45.x, v8[4]);
        v8[5] = fmaf(ps, (float)x45.y, v8[5]);
        v8[6] = fmaf(ps, (float)x67.x, v8[6]);
        v8[7] = fmaf(ps, (float)x67.y, v8[7]);
    }
    float inv = 1.f / fmaxf(den, EPSV);
    #pragma unroll
    for (int j = 0; j < 8; ++j) v8[j] *= inv;

    if (MODE == 1) {
        if (g == 0) {   // lanes sub 0..7 of each quarter-wave write their node
            float4 ba = reinterpret_cast<const float4*>(bias)[2 * s8];
            float4 bb = reinterpret_cast<const float4*>(bias)[2 * s8 + 1];
            float o0 = elu_f(v8[0] + ba.x), o1 = elu_f(v8[1] + ba.y);
            float o2 = elu_f(v8[2] + ba.z), o3 = elu_f(v8[3] + ba.w);
            float o4 = elu_f(v8[4] + bb.x), o5 = elu_f(v8[5] + bb.y);
            float o6 = elu_f(v8[6] + bb.z), o7 = elu_f(v8[7] + bb.w);
            float* op = outp + (size_t)d * 64 + 8 * s8;
            *reinterpret_cast<float4*>(op)     = make_float4(o0, o1, o2, o3);
            *reinterpret_cast<float4*>(op + 4) = make_float4(o4, o5, o6, o7);
        }
    } else {
        // head-mean over H=4 (CH=16): xor 2,4 on s8 bits (within quarter-wave)
        #pragma unroll
        for (int j = 0; j < 8; ++j) {
            v8[j] += __shfl_xor(v8[j], 2);
            v8[j] += __shfl_xor(v8[j], 4);
        }
        if (sub < 2) {   // g==0, s8 in {0,1}: out channels 8*s8..8*s8+7
            float4 ba = reinterpret_cast<const float4*>(bias)[2 * s8];
            float4 bb = reinterpret_cast<const float4*>(bias)[2 * s8 + 1];
            float* op = outp + (size_t)d * 16 + 8 * s8;
            *reinterpret_cast<float4*>(op) = make_float4(
                0.25f * v8[0] + ba.x, 0.25f * v8[1] + ba.y,
                0.25f * v8[2] + ba.z, 0.25f * v8[3] + ba.w);
            *reinterpret_cast<float4*>(op + 4) = make_float4(
                0.25f * v8[4] + bb.x, 0.25f * v8[5] + bb.y,
                0.25f * v8[6] + bb.z, 0.25f * v8[7] + bb.w);
        }
    }
}

// ---------------- host ----------------
extern "C" void kernel_launch(void* const* d_in, const int* in_sizes, int n_in,
                              void* d_out, int out_size, void* d_ws, size_t ws_size,
                              hipStream_t stream)
{
    const float* x      = (const float*)d_in[0];
    const int*   ei     = (const int*)d_in[1];
    const float* W1     = (const float*)d_in[2];
    const float* a_src1 = (const float*)d_in[3];
    const float* a_dst1 = (const float*)d_in[4];
    const float* b1     = (const float*)d_in[5];
    const float* W2     = (const float*)d_in[6];
    const float* a_src2 = (const float*)d_in[7];
    const float* a_dst2 = (const float*)d_in[8];
    const float* b2     = (const float*)d_in[9];
    float* out = (float*)d_out;

    const int n = in_sizes[0] / 256;     // 50000
    const int E = in_sizes[1] / 2;       // 1600000
    const int* src = ei;
    const int* dst = ei + E;

    const int NSB   = (E + CHUNK - 1) / CHUNK;        // 196
    const int NBUCK = (n + 63) >> BSH;                // 782
    const int m     = NBUCK * NSB;                    // 153272
    const int nb    = (m + SCAN_SZ - 1) / SCAN_SZ;    // 75
    const int NTB   = (n + 31) / 32;                  // 1563 (32-node tiles)
    const int T1    = 280;                            // hist phase tiles
    const int T2    = 1020;                           // place phase tiles
    const int T3    = NTB - T1 - T2;                  // 263 (nodesort phase)

    size_t N64 = (size_t)n * 64;
    size_t N8  = (size_t)n * 8;
    _Float16* xlh  = (_Float16*)d_ws;                 // N*64 fp16 (both layers)
    float* hbuf    = (float*)(xlh + N64);             // N*64 f32 (h)
    float* asrc    = hbuf + N64;                      // N*8
    float* adst    = asrc + N8;                       // N*8
    int*   histm   = (int*)(adst + N8);               // m
    int*   part    = histm + m;                       // m
    int*   scandT  = part + m;                        // m (transposed)
    int*   sums    = scandT + m;                      // 512
    int*   bstart  = sums + 512;                      // NBUCK+1 (783)
    int*   offs    = bstart + NBUCK + 1;              // n+1 (50001)
    unsigned* ssrc = (unsigned*)(offs + n + 1);       // E (4B)
    unsigned short* ssrc2 = (unsigned short*)(ssrc + E);   // E (2B)
    (void)ws_size; (void)n_in; (void)out_size;

    // ----- phase A: hist + NT1 tiles [0, T1) -----
    hist_nt<256, 8, 8><<<NSB + T1, 256, 0, stream>>>(
        x, W1, a_src1, a_dst1, xlh, asrc, adst, n, dst, E, histm, NBUCK, NSB, 0);

    // ----- scans (scan3 writes transposed) -----
    scan1_kernel<<<nb, 256, 0, stream>>>(histm, part, sums, m);
    scan3_kernel<<<(m + 255) / 256, 256, 0, stream>>>(part, sums, scandT, bstart,
                                                      m, NSB, NBUCK, E, nb);

    // ----- phase B: sort_place + NT1 tiles [T1, T1+T2) -----
    place_nt<256, 8, 8><<<NSB + T2, 256, 0, stream>>>(
        x, W1, a_src1, a_dst1, xlh, asrc, adst, n,
        src, dst, E, scandT, NBUCK, NSB, ssrc, T1);

    // ----- phase C: bucket_nodesort + NT1 tiles [T1+T2, NTB) -----
    nodesort_nt<256, 8, 8><<<NBUCK + T3, 256, 0, stream>>>(
        x, W1, a_src1, a_dst1, xlh, asrc, adst, n,
        ssrc, bstart, ssrc2, offs, NBUCK, E, T1 + T2);

    // ----- Layer 1 aggregate: 256 -> 8x8, concat, +b1, ELU -----
    aggregate_csr<8, 8, 1><<<(n + 15) / 16, 256, 0, stream>>>(offs, ssrc2, asrc, adst,
                                                              xlh, b1, hbuf, n);

    // ----- Layer 2: 64 -> 4x16, mean heads, +b2 -----
    node_transform<64, 4, 16><<<NTB, 256, 0, stream>>>(
        hbuf, W2, a_src2, a_dst2, xlh, asrc, adst, n);
    aggregate_csr<4, 16, 2><<<(n + 15) / 16, 256, 0, stream>>>(offs, ssrc2, asrc, adst,
                                                               xlh, b2, out, n);
}